// Round 5
// baseline (127.672 us; speedup 1.0000x reference)
//
#include <hip/hip_runtime.h>

constexpr int NG  = 2048;   // gaussians
constexpr int DF  = 64;     // feature dim
constexpr int IW  = 128;
constexpr int IH  = 128;

#define P_NEAR 0.01f
#define P_BLUR 0.3f
#define P_AMIN (1.0f/255.0f)
#define P_AMAX 0.999f

// ---------------------------------------------------------------------------
__device__ inline void invert4x4(const float* m, float* inv) {
    inv[0]  =  m[5]*m[10]*m[15] - m[5]*m[11]*m[14] - m[9]*m[6]*m[15] + m[9]*m[7]*m[14] + m[13]*m[6]*m[11] - m[13]*m[7]*m[10];
    inv[4]  = -m[4]*m[10]*m[15] + m[4]*m[11]*m[14] + m[8]*m[6]*m[15] - m[8]*m[7]*m[14] - m[12]*m[6]*m[11] + m[12]*m[7]*m[10];
    inv[8]  =  m[4]*m[9]*m[15]  - m[4]*m[11]*m[13] - m[8]*m[5]*m[15] + m[8]*m[7]*m[13] + m[12]*m[5]*m[11] - m[12]*m[7]*m[9];
    inv[12] = -m[4]*m[9]*m[14]  + m[4]*m[10]*m[13] + m[8]*m[5]*m[14] - m[8]*m[6]*m[13] - m[12]*m[5]*m[10] + m[12]*m[6]*m[9];
    inv[1]  = -m[1]*m[10]*m[15] + m[1]*m[11]*m[14] + m[9]*m[2]*m[15] - m[9]*m[3]*m[14] - m[13]*m[2]*m[11] + m[13]*m[3]*m[10];
    inv[5]  =  m[0]*m[10]*m[15] - m[0]*m[11]*m[14] - m[8]*m[2]*m[15] + m[8]*m[3]*m[14] + m[12]*m[2]*m[11] - m[12]*m[3]*m[10];
    inv[9]  = -m[0]*m[9]*m[15]  + m[0]*m[11]*m[13] + m[8]*m[1]*m[15] - m[8]*m[3]*m[13] - m[12]*m[1]*m[11] + m[12]*m[3]*m[9];
    inv[13] =  m[0]*m[9]*m[14]  - m[0]*m[10]*m[13] - m[8]*m[1]*m[14] + m[8]*m[2]*m[13] + m[12]*m[1]*m[10] - m[12]*m[2]*m[9];
    inv[2]  =  m[1]*m[6]*m[15]  - m[1]*m[7]*m[14]  - m[5]*m[2]*m[15] + m[5]*m[3]*m[14] + m[13]*m[2]*m[7]  - m[13]*m[3]*m[6];
    inv[6]  = -m[0]*m[6]*m[15]  + m[0]*m[7]*m[14]  + m[4]*m[2]*m[15] - m[4]*m[3]*m[14] - m[12]*m[2]*m[7]  + m[12]*m[3]*m[6];
    inv[10] =  m[0]*m[5]*m[15]  - m[0]*m[7]*m[13]  - m[4]*m[1]*m[15] + m[4]*m[3]*m[13] + m[12]*m[1]*m[7]  - m[12]*m[3]*m[5];
    inv[14] = -m[0]*m[5]*m[14]  + m[0]*m[6]*m[13]  + m[4]*m[1]*m[14] - m[4]*m[2]*m[13] - m[12]*m[1]*m[6]  + m[12]*m[2]*m[5];
    inv[3]  = -m[1]*m[6]*m[11]  + m[1]*m[7]*m[10]  + m[5]*m[2]*m[11] - m[5]*m[3]*m[10] - m[9]*m[2]*m[7]   + m[9]*m[3]*m[6];
    inv[7]  =  m[0]*m[6]*m[11]  - m[0]*m[7]*m[10]  - m[4]*m[2]*m[11] + m[4]*m[3]*m[10] + m[8]*m[2]*m[7]   - m[8]*m[3]*m[6];
    inv[11] = -m[0]*m[5]*m[11]  + m[0]*m[7]*m[9]   + m[4]*m[1]*m[11] - m[4]*m[3]*m[9]  - m[8]*m[1]*m[7]   + m[8]*m[3]*m[5];
    inv[15] =  m[0]*m[5]*m[10]  - m[0]*m[6]*m[9]   - m[4]*m[1]*m[10] + m[4]*m[2]*m[9]  + m[8]*m[1]*m[6]   - m[8]*m[2]*m[5];
    float det = m[0]*inv[0] + m[1]*inv[4] + m[2]*inv[8] + m[3]*inv[12];
    det = 1.0f / det;
    #pragma unroll
    for (int i = 0; i < 16; ++i) inv[i] *= det;
}

// ===========================================================================
// LEGACY single-kernel path (fallback when workspace is too small)
// ===========================================================================
constexpr int NZ  = 8;
constexpr int RB  = 1024;
constexpr int CAP = 1024;

constexpr int L_T    = 0;
constexpr int L_CNT  = 512;
constexpr int L_SIDX = 528;
constexpr int L_OVL  = L_SIDX + CAP;
constexpr int L_PRM  = L_OVL;
constexpr int L_KEYS = L_PRM + CAP * 8;
constexpr int L_ACC  = L_OVL;
constexpr int ACC_ST = 66;
constexpr int L_TOTAL = L_OVL + NZ * 64 * ACC_ST;

__global__ __launch_bounds__(RB, 4) void fused_render_kernel(
    const float* __restrict__ means,  const float* __restrict__ quats,
    const float* __restrict__ scales, const float* __restrict__ opac_logits,
    const float* __restrict__ colors, const float* __restrict__ c2o,
    const float* __restrict__ Kmat,   float* __restrict__ out)
{
    extern __shared__ float lds[];
    int*                cnt  = (int*)(lds + L_CNT);
    int*                sidx = (int*)(lds + L_SIDX);
    unsigned long long* keys = (unsigned long long*)(lds + L_KEYS);
    float4*             prm4 = (float4*)(lds + L_PRM);

    const int tid  = threadIdx.x;
    const int lane = tid & 63;
    const int wv16 = tid >> 6;
    const int sz   = wv16 >> 1;
    const int hh   = wv16 & 1;
    const int tile = blockIdx.x;
    const int tx = (tile & 15) * 8;
    const int ty = (tile >> 4) * 8;
    const float px = tx + (lane & 7) + 0.5f;
    const float py = ty + (lane >> 3) + 0.5f;
    const float cxt = tx + 4.0f, cyt = ty + 4.0f;

    if (tid == 0) *cnt = 0;
    __syncthreads();

    {
        float inv[16];
        {
            float m[16];
            #pragma unroll
            for (int t = 0; t < 16; ++t) m[t] = c2o[t];
            invert4x4(m, inv);
        }
        const float fx = Kmat[0], fy = Kmat[4], cx = Kmat[2], cy = Kmat[5];

        #pragma unroll
        for (int c = 0; c < NG / RB; ++c) {
            const int g = c * RB + tid;
            float mx = means[g*3+0], my = means[g*3+1], mz = means[g*3+2];
            float X = inv[0]*mx + inv[1]*my + inv[2]*mz  + inv[3];
            float Y = inv[4]*mx + inv[5]*my + inv[6]*mz  + inv[7];
            float Z = inv[8]*mx + inv[9]*my + inv[10]*mz + inv[11];

            float qw = quats[g*4+0], qx = quats[g*4+1], qy = quats[g*4+2], qz = quats[g*4+3];
            float qn = rsqrtf(qw*qw + qx*qx + qy*qy + qz*qz);
            qw *= qn; qx *= qn; qy *= qn; qz *= qn;
            float R00 = 1.f - 2.f*(qy*qy + qz*qz), R01 = 2.f*(qx*qy - qw*qz), R02 = 2.f*(qx*qz + qw*qy);
            float R10 = 2.f*(qx*qy + qw*qz), R11 = 1.f - 2.f*(qx*qx + qz*qz), R12 = 2.f*(qy*qz - qw*qx);
            float R20 = 2.f*(qx*qz - qw*qy), R21 = 2.f*(qy*qz + qw*qx), R22 = 1.f - 2.f*(qx*qx + qy*qy);

            float s0 = expf(scales[g*3+0]), s1 = expf(scales[g*3+1]), s2 = expf(scales[g*3+2]);
            float M00 = R00*s0, M01 = R01*s1, M02 = R02*s2;
            float M10 = R10*s0, M11 = R11*s1, M12 = R12*s2;
            float M20 = R20*s0, M21 = R21*s1, M22 = R22*s2;

            float V00 = M00*M00 + M01*M01 + M02*M02;
            float V01 = M00*M10 + M01*M11 + M02*M12;
            float V02 = M00*M20 + M01*M21 + M02*M22;
            float V11 = M10*M10 + M11*M11 + M12*M12;
            float V12 = M10*M20 + M11*M21 + M12*M22;
            float V22 = M20*M20 + M21*M21 + M22*M22;

            float Rv[3][3] = {{inv[0],inv[1],inv[2]},{inv[4],inv[5],inv[6]},{inv[8],inv[9],inv[10]}};
            float Vm[3][3] = {{V00,V01,V02},{V01,V11,V12},{V02,V12,V22}};
            float Tm[3][3], C[3][3];
            #pragma unroll
            for (int r = 0; r < 3; ++r)
                #pragma unroll
                for (int cc = 0; cc < 3; ++cc)
                    Tm[r][cc] = Rv[r][0]*Vm[0][cc] + Rv[r][1]*Vm[1][cc] + Rv[r][2]*Vm[2][cc];
            #pragma unroll
            for (int r = 0; r < 3; ++r)
                #pragma unroll
                for (int cc = 0; cc < 3; ++cc)
                    C[r][cc] = Tm[r][0]*Rv[cc][0] + Tm[r][1]*Rv[cc][1] + Tm[r][2]*Rv[cc][2];

            float rz = 1.0f / Z;
            float j00 = fx*rz, j02 = -fx*X*rz*rz;
            float j11 = fy*rz, j12 = -fy*Y*rz*rz;

            float c00 = j00*j00*C[0][0] + 2.f*j00*j02*C[0][2] + j02*j02*C[2][2];
            float c01 = j00*j11*C[0][1] + j00*j12*C[0][2] + j02*j11*C[1][2] + j02*j12*C[2][2];
            float c11 = j11*j11*C[1][1] + 2.f*j11*j12*C[1][2] + j12*j12*C[2][2];

            float a = c00 + P_BLUR;
            float b = c01;
            float cc_ = c11 + P_BLUR;
            float det = a*cc_ - b*b;

            float pmx = fx*X*rz + cx;
            float pmy = fy*Y*rz + cy;

            float lam = 0.5f*(a + cc_) + sqrtf(fmaxf(0.25f*(a - cc_)*(a - cc_) + b*b, 1e-12f));
            float radius = 3.0f * sqrtf(lam);
            bool valid = (Z > P_NEAR) && (det > 0.0f) && (radius > 3.0f);

            float op = 1.0f / (1.0f + expf(-opac_logits[g]));

            bool sel = false;
            float cA = 0.f, cB = 0.f, cC2 = 0.f;
            if (valid) {
                float rdet = 1.0f / det;
                cA = cc_ * rdet; cB = -b * rdet; cC2 = a * rdet;
                float smax = logf(255.0f * op);
                if (smax > 0.f) {
                    float rx = sqrtf(2.f * a   * smax) * 1.0001f + 1e-3f;
                    float ry = sqrtf(2.f * cc_ * smax) * 1.0001f + 1e-3f;
                    sel = (fabsf(pmx - cxt) <= rx + 3.5f) && (fabsf(pmy - cyt) <= ry + 3.5f);
                }
            }

            unsigned long long m = __ballot(sel);
            int wbase = 0;
            if (lane == 0 && m) wbase = atomicAdd(cnt, (int)__popcll(m));
            wbase = __shfl(wbase, 0);
            if (sel) {
                int pos = wbase + (int)__popcll(m & ((1ull << lane) - 1ull));
                if (pos < CAP) {
                    prm4[pos*2]   = make_float4(pmx, pmy, cA, cB);
                    prm4[pos*2+1] = make_float4(cC2, op, __int_as_float(g), 0.f);
                    keys[pos] = ((unsigned long long)__float_as_uint(Z) << 32) | (unsigned)g;
                }
            }
        }
    }
    __syncthreads();
    int L = *cnt;
    if (L > CAP) L = CAP;

    {
        int padL = (L + 1) & ~1;
        if (tid < padL - L) keys[L + tid] = ~0ull;
        __syncthreads();
        const ulonglong2* k2 = (const ulonglong2*)keys;
        if (tid < L) {
            unsigned long long kk = keys[tid];
            int rank = 0;
            #pragma unroll 2
            for (int c = 0; c < padL / 2; ++c) {
                ulonglong2 q = k2[c];
                rank += (q.x < kk) + (q.y < kk);
            }
            sidx[rank] = tid;
        }
    }
    __syncthreads();

    float acc[32];
    #pragma unroll
    for (int f = 0; f < 32; ++f) acc[f] = 0.f;
    float T = 1.0f;

    {
        const int r0 = (sz * L) >> 3;
        const int r1 = ((sz + 1) * L) >> 3;
        const float4* cph = (const float4*)colors + hh * 8;
        if (r1 > r0) {
            int k = sidx[r0];
            float4 e0 = prm4[k*2], e1 = prm4[k*2+1];
            for (int r = r0; r < r1; ++r) {
                int kn = (r + 1 < r1) ? sidx[r + 1] : k;
                float4 n0 = prm4[kn*2], n1 = prm4[kn*2+1];

                float dx = px - e0.x, dy = py - e0.y;
                float sig = 0.5f*(e0.z*dx*dx + e1.x*dy*dy) + e0.w*dx*dy;
                float al = fminf(e1.y * __expf(-sig), P_AMAX);
                al = (sig >= 0.f && al >= P_AMIN) ? al : 0.f;

                if (__ballot(al > 0.f)) {
                    float wv = T * al;
                    const float4* crow = cph + (size_t)(unsigned)__float_as_int(e1.z) * 16;
                    #pragma unroll
                    for (int q = 0; q < 8; ++q) {
                        float4 cv = crow[q];
                        acc[4*q+0] = fmaf(wv, cv.x, acc[4*q+0]);
                        acc[4*q+1] = fmaf(wv, cv.y, acc[4*q+1]);
                        acc[4*q+2] = fmaf(wv, cv.z, acc[4*q+2]);
                        acc[4*q+3] = fmaf(wv, cv.w, acc[4*q+3]);
                    }
                    T *= (1.f - al);
                    if (!__ballot(T >= 1e-6f)) break;
                }
                e0 = n0; e1 = n1; k = kn;
            }
        }
    }

    if (hh == 0) lds[L_T + sz*64 + lane] = T;
    __syncthreads();
    {
        float* ab = lds + L_ACC + (size_t)(sz * 64 + lane) * ACC_ST + hh * 32;
        #pragma unroll
        for (int q = 0; q < 16; ++q)
            *(float2*)(ab + 2*q) = make_float2(acc[2*q], acc[2*q+1]);
    }
    __syncthreads();

    {
        int p  = tid >> 4;
        int f0 = (tid & 15) * 4;
        float r0, r1, r2, r3;
        const float* ab = lds + L_ACC + (size_t)((NZ-1)*64 + p) * ACC_ST + f0;
        { float2 u = *(const float2*)ab, v = *(const float2*)(ab + 2);
          r0 = u.x; r1 = u.y; r2 = v.x; r3 = v.y; }
        #pragma unroll
        for (int s = NZ - 2; s >= 0; --s) {
            float Ts = lds[L_T + s*64 + p];
            const float* as_ = lds + L_ACC + (size_t)(s*64 + p) * ACC_ST + f0;
            float2 u = *(const float2*)as_, v = *(const float2*)(as_ + 2);
            r0 = fmaf(Ts, r0, u.x); r1 = fmaf(Ts, r1, u.y);
            r2 = fmaf(Ts, r2, v.x); r3 = fmaf(Ts, r3, v.y);
        }
        int pyg = ty + (p >> 3), pxg = tx + (p & 7);
        float* op_ = out + (size_t)(pyg * IW + pxg) * DF + f0;
        *(float4*)op_ = make_float4(r0, r1, r2, r3);
    }
}

// ===========================================================================
// 5-kernel pipeline.
// R4 post-mortem: raster 42us @ VALUBusy 47%.  Remaining loss = (1) color
// loads issued at point-of-use inside the alpha-conditional -> ~150cy L2
// stall per row; (2) per-tile cull (ballot+prefix+8 barriers over 2048
// gaussians) duplicated 8x across the tile's (seg,fb) blocks.
// R5: cull ONCE per tile into workspace (K2b, +8MB ws); raster stages the
// compacted list with a plain coalesced memcpy; colors hoisted to loop top
// indexed by the param prefetched last iteration.  launch_bounds(512,7)
// caps VGPR at 73 (body ~64) to forbid a spill-squeeze.
// ===========================================================================
constexpr int ZSL    = 8;     // z-slices per raster block (= waves per block)
constexpr int NSEG   = 2;     // z-segments per tile
constexpr int NFB    = 4;     // feature-blocks per tile (16 feats each)
constexpr int RTH    = 512;   // raster block threads
constexpr int NTILES = 256;
constexpr int EST    = 12;    // epilogue stage stride (floats), 16B-aligned

// workspace layout (float offsets)
constexpr size_t WS_TMPA = 0;                       // [NG] float4 {pmx,pmy,cA,cB}
constexpr size_t WS_TMPB = WS_TMPA + NG*4;          // [NG] float4 {cC2,op,rx,ry}
constexpr size_t WS_ZB   = WS_TMPB + NG*4;          // [NG] uint z-key
constexpr size_t WS_SA   = WS_ZB   + NG;            // sorted A {pmx,pmy,cA,cB}
constexpr size_t WS_SB   = WS_SA   + NG*4;          // sorted B {cC2,op,rx,ry}
constexpr size_t WS_SC   = WS_SB   + NG*4;          // sorted cull {pmx,pmy,rx,ry}
constexpr size_t WS_SG   = WS_SC   + NG*4;          // sorted gaussian idx
constexpr size_t WS_T0   = WS_SG   + NG;            // [NTILES][64] seg0 transmittance
constexpr size_t WS_ACC1 = WS_T0   + NTILES*64;     // [NTILES][64][DF] seg1 partial
constexpr size_t WS_TCNT = WS_ACC1 + (size_t)NTILES*64*DF;   // [NTILES] int count
constexpr size_t WS_TPRM = WS_TCNT + NTILES;        // [NTILES][CAP][8] compacted lists
constexpr size_t WS_TOTAL= WS_TPRM + (size_t)NTILES*CAP*8;   // floats (~12.6 MB)

// ---- K1: per-gaussian preprocess (identical math to legacy phase 1) -------
__global__ __launch_bounds__(64) void preprocess_kernel(
    const float* __restrict__ means,  const float* __restrict__ quats,
    const float* __restrict__ scales, const float* __restrict__ opac_logits,
    const float* __restrict__ c2o,    const float* __restrict__ Kmat,
    float* __restrict__ ws)
{
    const int g = blockIdx.x * 64 + threadIdx.x;

    float inv[16];
    {
        float m[16];
        #pragma unroll
        for (int t = 0; t < 16; ++t) m[t] = c2o[t];
        invert4x4(m, inv);
    }
    const float fx = Kmat[0], fy = Kmat[4], cx = Kmat[2], cy = Kmat[5];

    float mx = means[g*3+0], my = means[g*3+1], mz = means[g*3+2];
    float X = inv[0]*mx + inv[1]*my + inv[2]*mz  + inv[3];
    float Y = inv[4]*mx + inv[5]*my + inv[6]*mz  + inv[7];
    float Z = inv[8]*mx + inv[9]*my + inv[10]*mz + inv[11];

    float qw = quats[g*4+0], qx = quats[g*4+1], qy = quats[g*4+2], qz = quats[g*4+3];
    float qn = rsqrtf(qw*qw + qx*qx + qy*qy + qz*qz);
    qw *= qn; qx *= qn; qy *= qn; qz *= qn;
    float R00 = 1.f - 2.f*(qy*qy + qz*qz), R01 = 2.f*(qx*qy - qw*qz), R02 = 2.f*(qx*qz + qw*qy);
    float R10 = 2.f*(qx*qy + qw*qz), R11 = 1.f - 2.f*(qx*qx + qz*qz), R12 = 2.f*(qy*qz - qw*qx);
    float R20 = 2.f*(qx*qz - qw*qy), R21 = 2.f*(qy*qz + qw*qx), R22 = 1.f - 2.f*(qx*qx + qy*qy);

    float s0 = expf(scales[g*3+0]), s1 = expf(scales[g*3+1]), s2 = expf(scales[g*3+2]);
    float M00 = R00*s0, M01 = R01*s1, M02 = R02*s2;
    float M10 = R10*s0, M11 = R11*s1, M12 = R12*s2;
    float M20 = R20*s0, M21 = R21*s1, M22 = R22*s2;

    float V00 = M00*M00 + M01*M01 + M02*M02;
    float V01 = M00*M10 + M01*M11 + M02*M12;
    float V02 = M00*M20 + M01*M21 + M02*M22;
    float V11 = M10*M10 + M11*M11 + M12*M12;
    float V12 = M10*M20 + M11*M21 + M12*M22;
    float V22 = M20*M20 + M21*M21 + M22*M22;

    float Rv[3][3] = {{inv[0],inv[1],inv[2]},{inv[4],inv[5],inv[6]},{inv[8],inv[9],inv[10]}};
    float Vm[3][3] = {{V00,V01,V02},{V01,V11,V12},{V02,V12,V22}};
    float Tm[3][3], C[3][3];
    #pragma unroll
    for (int r = 0; r < 3; ++r)
        #pragma unroll
        for (int cc = 0; cc < 3; ++cc)
            Tm[r][cc] = Rv[r][0]*Vm[0][cc] + Rv[r][1]*Vm[1][cc] + Rv[r][2]*Vm[2][cc];
    #pragma unroll
    for (int r = 0; r < 3; ++r)
        #pragma unroll
        for (int cc = 0; cc < 3; ++cc)
            C[r][cc] = Tm[r][0]*Rv[cc][0] + Tm[r][1]*Rv[cc][1] + Tm[r][2]*Rv[cc][2];

    float rz = 1.0f / Z;
    float j00 = fx*rz, j02 = -fx*X*rz*rz;
    float j11 = fy*rz, j12 = -fy*Y*rz*rz;

    float c00 = j00*j00*C[0][0] + 2.f*j00*j02*C[0][2] + j02*j02*C[2][2];
    float c01 = j00*j11*C[0][1] + j00*j12*C[0][2] + j02*j11*C[1][2] + j02*j12*C[2][2];
    float c11 = j11*j11*C[1][1] + 2.f*j11*j12*C[1][2] + j12*j12*C[2][2];

    float a = c00 + P_BLUR;
    float b = c01;
    float cc_ = c11 + P_BLUR;
    float det = a*cc_ - b*b;

    float pmx = fx*X*rz + cx;
    float pmy = fy*Y*rz + cy;

    float lam = 0.5f*(a + cc_) + sqrtf(fmaxf(0.25f*(a - cc_)*(a - cc_) + b*b, 1e-12f));
    float radius = 3.0f * sqrtf(lam);
    bool valid = (Z > P_NEAR) && (det > 0.0f) && (radius > 3.0f);

    float op = 1.0f / (1.0f + expf(-opac_logits[g]));

    float cA = 0.f, cB = 0.f, cC2 = 0.f, rx = -1e9f, ry = -1e9f;
    if (valid) {
        float rdet = 1.0f / det;
        cA = cc_ * rdet; cB = -b * rdet; cC2 = a * rdet;
        float smax = logf(255.0f * op);
        if (smax > 0.f) {
            rx = sqrtf(2.f * a   * smax) * 1.0001f + 1e-3f;
            ry = sqrtf(2.f * cc_ * smax) * 1.0001f + 1e-3f;
        }
    }

    ((float4*)(ws + WS_TMPA))[g] = make_float4(pmx, pmy, cA, cB);
    ((float4*)(ws + WS_TMPB))[g] = make_float4(cC2, op, rx, ry);
    ((unsigned*)(ws + WS_ZB))[g] = __float_as_uint(Z);   // Z>0 for contributors: uint order == float order
}

// ---- K2: global stable rank-sort by (z,idx) + scatter params --------------
// 32 blocks x 512 threads; 64 keys/block; 8-way split scan of all 2048 keys.
__global__ __launch_bounds__(512) void sort_scatter_kernel(float* __restrict__ ws)
{
    __shared__ int cnt[8][64];
    const int lane = threadIdx.x & 63;
    const int part = threadIdx.x >> 6;
    const int g = blockIdx.x * 64 + lane;
    const unsigned* zb = (const unsigned*)(ws + WS_ZB);
    const unsigned zk = zb[g];
    const uint4* z4 = (const uint4*)zb;

    int c = 0;
    for (int i = part*64; i < part*64 + 64; ++i) {   // wave-uniform broadcast loads
        uint4 q = z4[i];
        const int j = i * 4;
        c += (q.x < zk || (q.x == zk && j+0 < g)) ? 1 : 0;
        c += (q.y < zk || (q.y == zk && j+1 < g)) ? 1 : 0;
        c += (q.z < zk || (q.z == zk && j+2 < g)) ? 1 : 0;
        c += (q.w < zk || (q.w == zk && j+3 < g)) ? 1 : 0;
    }
    cnt[part][lane] = c;
    __syncthreads();
    if (part == 0) {
        int rank = 0;
        #pragma unroll
        for (int e = 0; e < 8; ++e) rank += cnt[e][lane];
        float4 A = ((const float4*)(ws + WS_TMPA))[g];
        float4 B = ((const float4*)(ws + WS_TMPB))[g];
        ((float4*)(ws + WS_SA))[rank] = A;
        ((float4*)(ws + WS_SB))[rank] = B;
        ((float4*)(ws + WS_SC))[rank] = make_float4(A.x, A.y, B.z, B.w);  // cull-packed
        ((int*)  (ws + WS_SG))[rank] = g;
    }
}

// ---- K2b: per-tile cull, ONCE.  256 blocks x 512 thr.  Order-preserving
// compaction of the globally z-sorted list into ws (list + count). ---------
__global__ __launch_bounds__(512) void cull_tile_kernel(float* __restrict__ ws)
{
    __shared__ int s_wcnt[8];
    const int tid  = threadIdx.x;
    const int lane = tid & 63;
    const int w    = tid >> 6;
    const int tile = blockIdx.x;
    const int tx = (tile & 15) * 8, ty = (tile >> 4) * 8;
    const float cxt = tx + 4.0f, cyt = ty + 4.0f;

    const float4* sA = (const float4*)(ws + WS_SA);
    const float4* sB = (const float4*)(ws + WS_SB);
    const float4* sC = (const float4*)(ws + WS_SC);
    const int*    sG = (const int*)  (ws + WS_SG);
    float4* tp = (float4*)(ws + WS_TPRM + (size_t)tile * CAP * 8);

    int Lrun = 0;
    #pragma unroll
    for (int ch = 0; ch < NG/RTH; ++ch) {
        const int j = ch*RTH + tid;
        float4 C = sC[j];
        bool sel = (fabsf(C.x - cxt) <= C.z + 3.5f) && (fabsf(C.y - cyt) <= C.w + 3.5f);
        unsigned long long m = __ballot(sel);
        if (lane == 0) s_wcnt[w] = (int)__popcll(m);
        __syncthreads();
        int pre = 0, tot = 0;
        #pragma unroll
        for (int e = 0; e < 8; ++e) { int cw = s_wcnt[e]; pre += (e < w) ? cw : 0; tot += cw; }
        if (sel) {
            int pos = Lrun + pre + (int)__popcll(m & ((1ull << lane) - 1ull));
            if (pos < CAP) {
                float4 A = sA[j], B = sB[j];
                tp[pos*2]   = A;
                tp[pos*2+1] = make_float4(B.x, B.y, __int_as_float(sG[j]), 0.f);
            }
        }
        Lrun += tot;
        __syncthreads();   // s_wcnt reuse
    }
    if (tid == 0) ((int*)(ws + WS_TCNT))[tile] = (Lrun < CAP) ? Lrun : CAP;
}

// ---- K3: raster. grid = NTILES*NSEG*NFB = 2048; block = 512 thr = 8 waves -
// bid -> tile = bid>>3 (8 blocks of a tile CONSECUTIVE -> spread over CUs),
// k = bid&7: seg = k>>2 (z-segment), fb = k&3 (16-feature block).
// Stages the PRE-CULLED tile list (plain coalesced copy), then wave w
// composites z-slice v = seg*8+w, features fb*16..+15, acc[16].  Colors
// loaded at loop top via the param prefetched last iteration.
__global__ __launch_bounds__(RTH, 7) void raster_kernel(
    const float* __restrict__ colors, float* __restrict__ ws,
    float* __restrict__ out)
{
    __shared__ float ureg[CAP*8];        // staged prm list; epilogue overlays
    __shared__ float Tlds[ZSL*64];

    const int tid  = threadIdx.x;
    const int lane = tid & 63;
    const int w    = tid >> 6;           // wave 0..7 = z-slice within segment
    const int b    = blockIdx.x;
    const int tile = b >> 3;
    const int k    = b & 7;
    const int seg  = k >> 2;
    const int fb   = k & 3;
    const int tx = (tile & 15) * 8, ty = (tile >> 4) * 8;
    const float px = tx + (lane & 7) + 0.5f;
    const float py = ty + (lane >> 3) + 0.5f;

    float4* prm4 = (float4*)ureg;
    const int L = ((const int*)(ws + WS_TCNT))[tile];
    {   // coalesced copy of compacted list -> LDS (2L float4s)
        const float4* tp = (const float4*)(ws + WS_TPRM + (size_t)tile * CAP * 8);
        for (int i = tid; i < 2*L; i += RTH) prm4[i] = tp[i];
    }
    __syncthreads();

    // ---- composite: slice v = seg*8 + w, rows [v*L/16, (v+1)*L/16)
    float acc[16];
    #pragma unroll
    for (int i = 0; i < 16; ++i) acc[i] = 0.f;
    float T = 1.0f;
    {
        const int v  = seg * ZSL + w;
        const int r0 = (v * L) >> 4;
        const int r1 = ((v + 1) * L) >> 4;
        const float4* cph = (const float4*)colors + fb * 4;
        if (r1 > r0) {
            float4 e0 = prm4[2*r0], e1 = prm4[2*r0+1];
            for (int r = r0; r < r1; ++r) {
                // colors for CURRENT row; e1 was prefetched last iteration,
                // so these loads issue before the alpha math that covers them
                const float4* crow = cph + (size_t)(unsigned)__float_as_int(e1.z) * (DF/4);
                float4 c0 = crow[0], c1 = crow[1], c2 = crow[2], c3 = crow[3];

                const int rn = (r + 1 < r1) ? r + 1 : r;
                float4 n0 = prm4[2*rn], n1 = prm4[2*rn+1];   // prefetch next params

                float dx = px - e0.x, dy = py - e0.y;
                float sig = 0.5f*(e0.z*dx*dx + e1.x*dy*dy) + e0.w*dx*dy;
                float al = fminf(e1.y * __expf(-sig), P_AMAX);
                al = (sig >= 0.f && al >= P_AMIN) ? al : 0.f;

                if (__ballot(al > 0.f)) {
                    float wv = T * al;
                    acc[0]  = fmaf(wv, c0.x, acc[0]);
                    acc[1]  = fmaf(wv, c0.y, acc[1]);
                    acc[2]  = fmaf(wv, c0.z, acc[2]);
                    acc[3]  = fmaf(wv, c0.w, acc[3]);
                    acc[4]  = fmaf(wv, c1.x, acc[4]);
                    acc[5]  = fmaf(wv, c1.y, acc[5]);
                    acc[6]  = fmaf(wv, c1.z, acc[6]);
                    acc[7]  = fmaf(wv, c1.w, acc[7]);
                    acc[8]  = fmaf(wv, c2.x, acc[8]);
                    acc[9]  = fmaf(wv, c2.y, acc[9]);
                    acc[10] = fmaf(wv, c2.z, acc[10]);
                    acc[11] = fmaf(wv, c2.w, acc[11]);
                    acc[12] = fmaf(wv, c3.x, acc[12]);
                    acc[13] = fmaf(wv, c3.y, acc[13]);
                    acc[14] = fmaf(wv, c3.z, acc[14]);
                    acc[15] = fmaf(wv, c3.w, acc[15]);
                    T *= (1.f - al);
                    if (!__ballot(T >= 1e-6f)) break;   // whole wave saturated
                }
                e0 = n0; e1 = n1;
            }
        }
    }

    // ---- stage T; the barrier also ends prm reads before staging overlay
    Tlds[w*64 + lane] = T;
    __syncthreads();

    if (seg == 0 && fb == 0 && tid < 64) {
        float tp = 1.f;
        #pragma unroll
        for (int s = 0; s < ZSL; ++s) tp *= Tlds[s*64 + tid];
        ws[WS_T0 + tile*64 + tid] = tp;
    }

    // ---- 4 passes x 4 features: stage slice accs + affine combine + store.
    // Stage row = w*64+lane (512 rows, stride EST=12; max idx 6135 < 8192).
    #pragma unroll
    for (int pass = 0; pass < 4; ++pass) {
        float* ab = ureg + (w*64 + lane) * EST;
        *(float4*)ab = make_float4(acc[pass*4+0], acc[pass*4+1], acc[pass*4+2], acc[pass*4+3]);
        __syncthreads();
        if (tid < 256) {
            const int p = tid >> 2, c = tid & 3;     // pixel 0..63, feat-in-pass
            float r = ureg[((ZSL-1)*64 + p)*EST + c];
            #pragma unroll
            for (int s = ZSL-2; s >= 0; --s)
                r = fmaf(Tlds[s*64 + p], r, ureg[(s*64 + p)*EST + c]);
            const int pxg = tx + (p & 7), pyg = ty + (p >> 3);
            const int fi = fb*16 + pass*4 + c;
            if (seg == 0) out[(size_t)(pyg*IW + pxg)*DF + fi] = r;
            else          ws[WS_ACC1 + ((size_t)tile*64 + p)*DF + fi] = r;
        }
        __syncthreads();
    }
}

// ---- K4: out = A0 + T0 * A1 ----------------------------------------------
__global__ __launch_bounds__(1024) void combine_kernel(
    float* __restrict__ out, const float* __restrict__ ws)
{
    const int tile = blockIdx.x;
    const int p  = threadIdx.x >> 4;
    const int f0 = (threadIdx.x & 15) * 4;
    const int pxg = (tile & 15)*8 + (p & 7);
    const int pyg = (tile >> 4)*8 + (p >> 3);
    const float T0 = ws[WS_T0 + tile*64 + p];
    const float4 a1 = *(const float4*)(ws + WS_ACC1 + ((size_t)tile*64 + p)*DF + f0);
    float4* o = (float4*)(out + (size_t)(pyg*IW + pxg)*DF + f0);
    float4 v = *o;
    v.x = fmaf(T0, a1.x, v.x);
    v.y = fmaf(T0, a1.y, v.y);
    v.z = fmaf(T0, a1.z, v.z);
    v.w = fmaf(T0, a1.w, v.w);
    *o = v;
}

// ---------------------------------------------------------------------------
extern "C" void kernel_launch(void* const* d_in, const int* in_sizes, int n_in,
                              void* d_out, int out_size, void* d_ws, size_t ws_size,
                              hipStream_t stream) {
    const float* means  = (const float*)d_in[0];
    const float* quats  = (const float*)d_in[1];
    const float* scales = (const float*)d_in[2];
    const float* opac   = (const float*)d_in[3];
    const float* colors = (const float*)d_in[4];
    const float* c2o    = (const float*)d_in[5];
    const float* Kmat   = (const float*)d_in[6];
    float* out = (float*)d_out;

    if (ws_size >= WS_TOTAL * sizeof(float)) {
        float* ws = (float*)d_ws;
        preprocess_kernel  <<<NG/64,              64,  0, stream>>>(means, quats, scales, opac, c2o, Kmat, ws);
        sort_scatter_kernel<<<NG/64,              512, 0, stream>>>(ws);
        cull_tile_kernel   <<<NTILES,             512, 0, stream>>>(ws);
        raster_kernel      <<<NTILES*NSEG*NFB,    RTH, 0, stream>>>(colors, ws, out);
        combine_kernel     <<<NTILES,             1024,0, stream>>>(out, ws);
    } else {
        // fallback: legacy fused single-kernel path
        (void)hipFuncSetAttribute((const void*)fused_render_kernel,
                                  hipFuncAttributeMaxDynamicSharedMemorySize,
                                  L_TOTAL * 4);
        fused_render_kernel<<<IH*IW/64, RB, L_TOTAL*4, stream>>>(
            means, quats, scales, opac, colors, c2o, Kmat, out);
    }
}

// Round 6
// 110.200 us; speedup vs baseline: 1.1586x; 1.1586x over previous
//
#include <hip/hip_runtime.h>

constexpr int NG  = 2048;   // gaussians
constexpr int DF  = 64;     // feature dim
constexpr int IW  = 128;
constexpr int IH  = 128;

#define P_NEAR 0.01f
#define P_BLUR 0.3f
#define P_AMIN (1.0f/255.0f)
#define P_AMAX 0.999f

// ---------------------------------------------------------------------------
__device__ inline void invert4x4(const float* m, float* inv) {
    inv[0]  =  m[5]*m[10]*m[15] - m[5]*m[11]*m[14] - m[9]*m[6]*m[15] + m[9]*m[7]*m[14] + m[13]*m[6]*m[11] - m[13]*m[7]*m[10];
    inv[4]  = -m[4]*m[10]*m[15] + m[4]*m[11]*m[14] + m[8]*m[6]*m[15] - m[8]*m[7]*m[14] - m[12]*m[6]*m[11] + m[12]*m[7]*m[10];
    inv[8]  =  m[4]*m[9]*m[15]  - m[4]*m[11]*m[13] - m[8]*m[5]*m[15] + m[8]*m[7]*m[13] + m[12]*m[5]*m[11] - m[12]*m[7]*m[9];
    inv[12] = -m[4]*m[9]*m[14]  + m[4]*m[10]*m[13] + m[8]*m[5]*m[14] - m[8]*m[6]*m[13] - m[12]*m[5]*m[10] + m[12]*m[6]*m[9];
    inv[1]  = -m[1]*m[10]*m[15] + m[1]*m[11]*m[14] + m[9]*m[2]*m[15] - m[9]*m[3]*m[14] - m[13]*m[2]*m[11] + m[13]*m[3]*m[10];
    inv[5]  =  m[0]*m[10]*m[15] - m[0]*m[11]*m[14] - m[8]*m[2]*m[15] + m[8]*m[3]*m[14] + m[12]*m[2]*m[11] - m[12]*m[3]*m[10];
    inv[9]  = -m[0]*m[9]*m[15]  + m[0]*m[11]*m[13] + m[8]*m[1]*m[15] - m[8]*m[3]*m[13] - m[12]*m[1]*m[11] + m[12]*m[3]*m[9];
    inv[13] =  m[0]*m[9]*m[14]  - m[0]*m[10]*m[13] - m[8]*m[1]*m[14] + m[8]*m[2]*m[13] + m[12]*m[1]*m[10] - m[12]*m[2]*m[9];
    inv[2]  =  m[1]*m[6]*m[15]  - m[1]*m[7]*m[14]  - m[5]*m[2]*m[15] + m[5]*m[3]*m[14] + m[13]*m[2]*m[7]  - m[13]*m[3]*m[6];
    inv[6]  = -m[0]*m[6]*m[15]  + m[0]*m[7]*m[14]  + m[4]*m[2]*m[15] - m[4]*m[3]*m[14] - m[12]*m[2]*m[7]  + m[12]*m[3]*m[6];
    inv[10] =  m[0]*m[5]*m[15]  - m[0]*m[7]*m[13]  - m[4]*m[1]*m[15] + m[4]*m[3]*m[13] + m[12]*m[1]*m[7]  - m[12]*m[3]*m[5];
    inv[14] = -m[0]*m[5]*m[14]  + m[0]*m[6]*m[13]  + m[4]*m[1]*m[14] - m[4]*m[2]*m[13] - m[12]*m[1]*m[6]  + m[12]*m[2]*m[5];
    inv[3]  = -m[1]*m[6]*m[11]  + m[1]*m[7]*m[10]  + m[5]*m[2]*m[11] - m[5]*m[3]*m[10] - m[9]*m[2]*m[7]   + m[9]*m[3]*m[6];
    inv[7]  =  m[0]*m[6]*m[11]  - m[0]*m[7]*m[10]  - m[4]*m[2]*m[11] + m[4]*m[3]*m[10] + m[8]*m[2]*m[7]   - m[8]*m[3]*m[6];
    inv[11] = -m[0]*m[5]*m[11]  + m[0]*m[7]*m[9]   + m[4]*m[1]*m[11] - m[4]*m[3]*m[9]  - m[8]*m[1]*m[7]   + m[8]*m[3]*m[5];
    inv[15] =  m[0]*m[5]*m[10]  - m[0]*m[6]*m[9]   - m[4]*m[1]*m[10] + m[4]*m[2]*m[9]  + m[8]*m[1]*m[6]   - m[8]*m[2]*m[5];
    float det = m[0]*inv[0] + m[1]*inv[4] + m[2]*inv[8] + m[3]*inv[12];
    det = 1.0f / det;
    #pragma unroll
    for (int i = 0; i < 16; ++i) inv[i] *= det;
}

// ===========================================================================
// LEGACY single-kernel path (fallback when workspace is too small)
// ===========================================================================
constexpr int NZ  = 8;
constexpr int RB  = 1024;
constexpr int CAP = 1024;

constexpr int L_T    = 0;
constexpr int L_CNT  = 512;
constexpr int L_SIDX = 528;
constexpr int L_OVL  = L_SIDX + CAP;
constexpr int L_PRM  = L_OVL;
constexpr int L_KEYS = L_PRM + CAP * 8;
constexpr int L_ACC  = L_OVL;
constexpr int ACC_ST = 66;
constexpr int L_TOTAL = L_OVL + NZ * 64 * ACC_ST;

__global__ __launch_bounds__(RB, 4) void fused_render_kernel(
    const float* __restrict__ means,  const float* __restrict__ quats,
    const float* __restrict__ scales, const float* __restrict__ opac_logits,
    const float* __restrict__ colors, const float* __restrict__ c2o,
    const float* __restrict__ Kmat,   float* __restrict__ out)
{
    extern __shared__ float lds[];
    int*                cnt  = (int*)(lds + L_CNT);
    int*                sidx = (int*)(lds + L_SIDX);
    unsigned long long* keys = (unsigned long long*)(lds + L_KEYS);
    float4*             prm4 = (float4*)(lds + L_PRM);

    const int tid  = threadIdx.x;
    const int lane = tid & 63;
    const int wv16 = tid >> 6;
    const int sz   = wv16 >> 1;
    const int hh   = wv16 & 1;
    const int tile = blockIdx.x;
    const int tx = (tile & 15) * 8;
    const int ty = (tile >> 4) * 8;
    const float px = tx + (lane & 7) + 0.5f;
    const float py = ty + (lane >> 3) + 0.5f;
    const float cxt = tx + 4.0f, cyt = ty + 4.0f;

    if (tid == 0) *cnt = 0;
    __syncthreads();

    {
        float inv[16];
        {
            float m[16];
            #pragma unroll
            for (int t = 0; t < 16; ++t) m[t] = c2o[t];
            invert4x4(m, inv);
        }
        const float fx = Kmat[0], fy = Kmat[4], cx = Kmat[2], cy = Kmat[5];

        #pragma unroll
        for (int c = 0; c < NG / RB; ++c) {
            const int g = c * RB + tid;
            float mx = means[g*3+0], my = means[g*3+1], mz = means[g*3+2];
            float X = inv[0]*mx + inv[1]*my + inv[2]*mz  + inv[3];
            float Y = inv[4]*mx + inv[5]*my + inv[6]*mz  + inv[7];
            float Z = inv[8]*mx + inv[9]*my + inv[10]*mz + inv[11];

            float qw = quats[g*4+0], qx = quats[g*4+1], qy = quats[g*4+2], qz = quats[g*4+3];
            float qn = rsqrtf(qw*qw + qx*qx + qy*qy + qz*qz);
            qw *= qn; qx *= qn; qy *= qn; qz *= qn;
            float R00 = 1.f - 2.f*(qy*qy + qz*qz), R01 = 2.f*(qx*qy - qw*qz), R02 = 2.f*(qx*qz + qw*qy);
            float R10 = 2.f*(qx*qy + qw*qz), R11 = 1.f - 2.f*(qx*qx + qz*qz), R12 = 2.f*(qy*qz - qw*qx);
            float R20 = 2.f*(qx*qz - qw*qy), R21 = 2.f*(qy*qz + qw*qx), R22 = 1.f - 2.f*(qx*qx + qy*qy);

            float s0 = expf(scales[g*3+0]), s1 = expf(scales[g*3+1]), s2 = expf(scales[g*3+2]);
            float M00 = R00*s0, M01 = R01*s1, M02 = R02*s2;
            float M10 = R10*s0, M11 = R11*s1, M12 = R12*s2;
            float M20 = R20*s0, M21 = R21*s1, M22 = R22*s2;

            float V00 = M00*M00 + M01*M01 + M02*M02;
            float V01 = M00*M10 + M01*M11 + M02*M12;
            float V02 = M00*M20 + M01*M21 + M02*M22;
            float V11 = M10*M10 + M11*M11 + M12*M12;
            float V12 = M10*M20 + M11*M21 + M12*M22;
            float V22 = M20*M20 + M21*M21 + M22*M22;

            float Rv[3][3] = {{inv[0],inv[1],inv[2]},{inv[4],inv[5],inv[6]},{inv[8],inv[9],inv[10]}};
            float Vm[3][3] = {{V00,V01,V02},{V01,V11,V12},{V02,V12,V22}};
            float Tm[3][3], C[3][3];
            #pragma unroll
            for (int r = 0; r < 3; ++r)
                #pragma unroll
                for (int cc = 0; cc < 3; ++cc)
                    Tm[r][cc] = Rv[r][0]*Vm[0][cc] + Rv[r][1]*Vm[1][cc] + Rv[r][2]*Vm[2][cc];
            #pragma unroll
            for (int r = 0; r < 3; ++r)
                #pragma unroll
                for (int cc = 0; cc < 3; ++cc)
                    C[r][cc] = Tm[r][0]*Rv[cc][0] + Tm[r][1]*Rv[cc][1] + Tm[r][2]*Rv[cc][2];

            float rz = 1.0f / Z;
            float j00 = fx*rz, j02 = -fx*X*rz*rz;
            float j11 = fy*rz, j12 = -fy*Y*rz*rz;

            float c00 = j00*j00*C[0][0] + 2.f*j00*j02*C[0][2] + j02*j02*C[2][2];
            float c01 = j00*j11*C[0][1] + j00*j12*C[0][2] + j02*j11*C[1][2] + j02*j12*C[2][2];
            float c11 = j11*j11*C[1][1] + 2.f*j11*j12*C[1][2] + j12*j12*C[2][2];

            float a = c00 + P_BLUR;
            float b = c01;
            float cc_ = c11 + P_BLUR;
            float det = a*cc_ - b*b;

            float pmx = fx*X*rz + cx;
            float pmy = fy*Y*rz + cy;

            float lam = 0.5f*(a + cc_) + sqrtf(fmaxf(0.25f*(a - cc_)*(a - cc_) + b*b, 1e-12f));
            float radius = 3.0f * sqrtf(lam);
            bool valid = (Z > P_NEAR) && (det > 0.0f) && (radius > 3.0f);

            float op = 1.0f / (1.0f + expf(-opac_logits[g]));

            bool sel = false;
            float cA = 0.f, cB = 0.f, cC2 = 0.f;
            if (valid) {
                float rdet = 1.0f / det;
                cA = cc_ * rdet; cB = -b * rdet; cC2 = a * rdet;
                float smax = logf(255.0f * op);
                if (smax > 0.f) {
                    float rx = sqrtf(2.f * a   * smax) * 1.0001f + 1e-3f;
                    float ry = sqrtf(2.f * cc_ * smax) * 1.0001f + 1e-3f;
                    sel = (fabsf(pmx - cxt) <= rx + 3.5f) && (fabsf(pmy - cyt) <= ry + 3.5f);
                }
            }

            unsigned long long m = __ballot(sel);
            int wbase = 0;
            if (lane == 0 && m) wbase = atomicAdd(cnt, (int)__popcll(m));
            wbase = __shfl(wbase, 0);
            if (sel) {
                int pos = wbase + (int)__popcll(m & ((1ull << lane) - 1ull));
                if (pos < CAP) {
                    prm4[pos*2]   = make_float4(pmx, pmy, cA, cB);
                    prm4[pos*2+1] = make_float4(cC2, op, __int_as_float(g), 0.f);
                    keys[pos] = ((unsigned long long)__float_as_uint(Z) << 32) | (unsigned)g;
                }
            }
        }
    }
    __syncthreads();
    int L = *cnt;
    if (L > CAP) L = CAP;

    {
        int padL = (L + 1) & ~1;
        if (tid < padL - L) keys[L + tid] = ~0ull;
        __syncthreads();
        const ulonglong2* k2 = (const ulonglong2*)keys;
        if (tid < L) {
            unsigned long long kk = keys[tid];
            int rank = 0;
            #pragma unroll 2
            for (int c = 0; c < padL / 2; ++c) {
                ulonglong2 q = k2[c];
                rank += (q.x < kk) + (q.y < kk);
            }
            sidx[rank] = tid;
        }
    }
    __syncthreads();

    float acc[32];
    #pragma unroll
    for (int f = 0; f < 32; ++f) acc[f] = 0.f;
    float T = 1.0f;

    {
        const int r0 = (sz * L) >> 3;
        const int r1 = ((sz + 1) * L) >> 3;
        const float4* cph = (const float4*)colors + hh * 8;
        if (r1 > r0) {
            int k = sidx[r0];
            float4 e0 = prm4[k*2], e1 = prm4[k*2+1];
            for (int r = r0; r < r1; ++r) {
                int kn = (r + 1 < r1) ? sidx[r + 1] : k;
                float4 n0 = prm4[kn*2], n1 = prm4[kn*2+1];

                float dx = px - e0.x, dy = py - e0.y;
                float sig = 0.5f*(e0.z*dx*dx + e1.x*dy*dy) + e0.w*dx*dy;
                float al = fminf(e1.y * __expf(-sig), P_AMAX);
                al = (sig >= 0.f && al >= P_AMIN) ? al : 0.f;

                if (__ballot(al > 0.f)) {
                    float wv = T * al;
                    const float4* crow = cph + (size_t)(unsigned)__float_as_int(e1.z) * 16;
                    #pragma unroll
                    for (int q = 0; q < 8; ++q) {
                        float4 cv = crow[q];
                        acc[4*q+0] = fmaf(wv, cv.x, acc[4*q+0]);
                        acc[4*q+1] = fmaf(wv, cv.y, acc[4*q+1]);
                        acc[4*q+2] = fmaf(wv, cv.z, acc[4*q+2]);
                        acc[4*q+3] = fmaf(wv, cv.w, acc[4*q+3]);
                    }
                    T *= (1.f - al);
                    if (!__ballot(T >= 1e-6f)) break;
                }
                e0 = n0; e1 = n1; k = kn;
            }
        }
    }

    if (hh == 0) lds[L_T + sz*64 + lane] = T;
    __syncthreads();
    {
        float* ab = lds + L_ACC + (size_t)(sz * 64 + lane) * ACC_ST + hh * 32;
        #pragma unroll
        for (int q = 0; q < 16; ++q)
            *(float2*)(ab + 2*q) = make_float2(acc[2*q], acc[2*q+1]);
    }
    __syncthreads();

    {
        int p  = tid >> 4;
        int f0 = (tid & 15) * 4;
        float r0, r1, r2, r3;
        const float* ab = lds + L_ACC + (size_t)((NZ-1)*64 + p) * ACC_ST + f0;
        { float2 u = *(const float2*)ab, v = *(const float2*)(ab + 2);
          r0 = u.x; r1 = u.y; r2 = v.x; r3 = v.y; }
        #pragma unroll
        for (int s = NZ - 2; s >= 0; --s) {
            float Ts = lds[L_T + s*64 + p];
            const float* as_ = lds + L_ACC + (size_t)(s*64 + p) * ACC_ST + f0;
            float2 u = *(const float2*)as_, v = *(const float2*)(as_ + 2);
            r0 = fmaf(Ts, r0, u.x); r1 = fmaf(Ts, r1, u.y);
            r2 = fmaf(Ts, r2, v.x); r3 = fmaf(Ts, r3, v.y);
        }
        int pyg = ty + (p >> 3), pxg = tx + (p & 7);
        float* op_ = out + (size_t)(pyg * IW + pxg) * DF + f0;
        *(float4*)op_ = make_float4(r0, r1, r2, r3);
    }
}

// ===========================================================================
// 4-kernel pipeline (R6).
// R5 post-mortem: top-5 = harness 256MiB workspace fills @41us (fixed
// overhead); kernels all <41us, bench flat vs R4 -> cull kernel + extra
// launch (~3.5us each) ate raster's gain.  Issue-bound model calibrated on
// R4: 24M wave-instrs <-> 47% VALUBusy x 42us.
// R6: (a) fuse preprocess+sort into ONE kernel (per-block redundant z-keys
// in LDS -> deterministic consistent ranks; wave0 preprocesses own 64 and
// scatters from registers); (b) NFB 4->2 with proven acc[32] shape: per-row
// 2x(18+32)=100 slots vs 4x34=136 (-26% instrs); (c) colors via
// readfirstlane (uniform -> s_load eligible), hoisted before alpha math.
// ===========================================================================
constexpr int ZSL    = 8;     // z-slices per raster block (= waves per block)
constexpr int NSEG   = 2;     // z-segments per tile
constexpr int NFB    = 2;     // feature-blocks per tile (32 feats each)
constexpr int RTH    = 512;   // raster block threads
constexpr int NTILES = 256;
constexpr int EST    = 12;    // epilogue stage stride (floats), 16B-aligned

// workspace layout (float offsets)
constexpr size_t WS_SA   = 0;                       // sorted A {pmx,pmy,cA,cB}
constexpr size_t WS_SB   = WS_SA   + NG*4;          // sorted B {cC2,op,rx,ry}
constexpr size_t WS_SC   = WS_SB   + NG*4;          // sorted cull {pmx,pmy,rx,ry}
constexpr size_t WS_SG   = WS_SC   + NG*4;          // sorted gaussian idx
constexpr size_t WS_T0   = WS_SG   + NG;            // [NTILES][64] seg0 transmittance
constexpr size_t WS_ACC1 = WS_T0   + NTILES*64;     // [NTILES][64][DF] seg1 partial
constexpr size_t WS_TCNT = WS_ACC1 + (size_t)NTILES*64*DF;   // [NTILES] int count
constexpr size_t WS_TPRM = WS_TCNT + NTILES;        // [NTILES][CAP][8] compacted lists
constexpr size_t WS_TOTAL= WS_TPRM + (size_t)NTILES*CAP*8;   // floats (~12.8 MB)

// ---- K12: fused preprocess + global stable z-sort + scatter ---------------
// 32 blocks x 512 thr.  Each block recomputes ALL 2048 z-keys into LDS
// (pure FMA, deterministic -> identical across blocks -> consistent ranks).
// Wave 0 does the full preprocess for the block's own 64 gaussians (kept in
// registers); 8 waves cooperatively rank those 64 against all 2048 keys;
// wave 0 scatters params to the sorted arrays.
__global__ __launch_bounds__(512) void prep_sort_kernel(
    const float* __restrict__ means,  const float* __restrict__ quats,
    const float* __restrict__ scales, const float* __restrict__ opac_logits,
    const float* __restrict__ c2o,    const float* __restrict__ Kmat,
    float* __restrict__ ws)
{
    __shared__ __align__(16) unsigned zlds[NG];
    __shared__ int cnt[8][64];
    const int tid  = threadIdx.x;
    const int lane = tid & 63;
    const int part = tid >> 6;
    const int b    = blockIdx.x;
    const int gown = b * 64 + lane;

    float inv[16];
    {
        float m[16];
        #pragma unroll
        for (int t = 0; t < 16; ++t) m[t] = c2o[t];
        invert4x4(m, inv);
    }
    const float fx = Kmat[0], fy = Kmat[4], cx = Kmat[2], cy = Kmat[5];

    // ---- all 2048 z-keys (4 per thread), deterministic across blocks
    #pragma unroll
    for (int u = 0; u < NG/512; ++u) {
        const int g = u*512 + tid;
        float mx = means[g*3+0], my = means[g*3+1], mz = means[g*3+2];
        float Z = inv[8]*mx + inv[9]*my + inv[10]*mz + inv[11];
        zlds[g] = __float_as_uint(Z);   // Z>0 for contributors: uint order == float order
    }

    // ---- wave 0: full preprocess of own gaussian (registers)
    float4 A = make_float4(0.f,0.f,0.f,0.f);
    float4 B = make_float4(0.f,0.f,-1e9f,-1e9f);
    if (part == 0) {
        const int g = gown;
        float mx = means[g*3+0], my = means[g*3+1], mz = means[g*3+2];
        float X = inv[0]*mx + inv[1]*my + inv[2]*mz  + inv[3];
        float Y = inv[4]*mx + inv[5]*my + inv[6]*mz  + inv[7];
        float Z = inv[8]*mx + inv[9]*my + inv[10]*mz + inv[11];

        float qw = quats[g*4+0], qx = quats[g*4+1], qy = quats[g*4+2], qz = quats[g*4+3];
        float qn = rsqrtf(qw*qw + qx*qx + qy*qy + qz*qz);
        qw *= qn; qx *= qn; qy *= qn; qz *= qn;
        float R00 = 1.f - 2.f*(qy*qy + qz*qz), R01 = 2.f*(qx*qy - qw*qz), R02 = 2.f*(qx*qz + qw*qy);
        float R10 = 2.f*(qx*qy + qw*qz), R11 = 1.f - 2.f*(qx*qx + qz*qz), R12 = 2.f*(qy*qz - qw*qx);
        float R20 = 2.f*(qx*qz - qw*qy), R21 = 2.f*(qy*qz + qw*qx), R22 = 1.f - 2.f*(qx*qx + qy*qy);

        float s0 = expf(scales[g*3+0]), s1 = expf(scales[g*3+1]), s2 = expf(scales[g*3+2]);
        float M00 = R00*s0, M01 = R01*s1, M02 = R02*s2;
        float M10 = R10*s0, M11 = R11*s1, M12 = R12*s2;
        float M20 = R20*s0, M21 = R21*s1, M22 = R22*s2;

        float V00 = M00*M00 + M01*M01 + M02*M02;
        float V01 = M00*M10 + M01*M11 + M02*M12;
        float V02 = M00*M20 + M01*M21 + M02*M22;
        float V11 = M10*M10 + M11*M11 + M12*M12;
        float V12 = M10*M20 + M11*M21 + M12*M22;
        float V22 = M20*M20 + M21*M21 + M22*M22;

        float Rv[3][3] = {{inv[0],inv[1],inv[2]},{inv[4],inv[5],inv[6]},{inv[8],inv[9],inv[10]}};
        float Vm[3][3] = {{V00,V01,V02},{V01,V11,V12},{V02,V12,V22}};
        float Tm[3][3], C[3][3];
        #pragma unroll
        for (int r = 0; r < 3; ++r)
            #pragma unroll
            for (int cc = 0; cc < 3; ++cc)
                Tm[r][cc] = Rv[r][0]*Vm[0][cc] + Rv[r][1]*Vm[1][cc] + Rv[r][2]*Vm[2][cc];
        #pragma unroll
        for (int r = 0; r < 3; ++r)
            #pragma unroll
            for (int cc = 0; cc < 3; ++cc)
                C[r][cc] = Tm[r][0]*Rv[cc][0] + Tm[r][1]*Rv[cc][1] + Tm[r][2]*Rv[cc][2];

        float rz = 1.0f / Z;
        float j00 = fx*rz, j02 = -fx*X*rz*rz;
        float j11 = fy*rz, j12 = -fy*Y*rz*rz;

        float c00 = j00*j00*C[0][0] + 2.f*j00*j02*C[0][2] + j02*j02*C[2][2];
        float c01 = j00*j11*C[0][1] + j00*j12*C[0][2] + j02*j11*C[1][2] + j02*j12*C[2][2];
        float c11 = j11*j11*C[1][1] + 2.f*j11*j12*C[1][2] + j12*j12*C[2][2];

        float a = c00 + P_BLUR;
        float bb = c01;
        float cc_ = c11 + P_BLUR;
        float det = a*cc_ - bb*bb;

        float pmx = fx*X*rz + cx;
        float pmy = fy*Y*rz + cy;

        float lam = 0.5f*(a + cc_) + sqrtf(fmaxf(0.25f*(a - cc_)*(a - cc_) + bb*bb, 1e-12f));
        float radius = 3.0f * sqrtf(lam);
        bool valid = (Z > P_NEAR) && (det > 0.0f) && (radius > 3.0f);

        float op = 1.0f / (1.0f + expf(-opac_logits[g]));

        float cA = 0.f, cB = 0.f, cC2 = 0.f, rx = -1e9f, ry = -1e9f;
        if (valid) {
            float rdet = 1.0f / det;
            cA = cc_ * rdet; cB = -bb * rdet; cC2 = a * rdet;
            float smax = logf(255.0f * op);
            if (smax > 0.f) {
                rx = sqrtf(2.f * a   * smax) * 1.0001f + 1e-3f;
                ry = sqrtf(2.f * cc_ * smax) * 1.0001f + 1e-3f;
            }
        }
        A = make_float4(pmx, pmy, cA, cB);
        B = make_float4(cC2, op, rx, ry);
    }
    __syncthreads();

    // ---- rank own 64 gaussians against all 2048 (z,idx) keys
    const unsigned kk = zlds[b*64 + lane];
    const uint4* zl4 = (const uint4*)zlds;
    int c = 0;
    #pragma unroll 4
    for (int i = part*64; i < part*64 + 64; ++i) {
        uint4 q = zl4[i];
        const int j = i * 4;
        c += (q.x < kk || (q.x == kk && j+0 < gown)) ? 1 : 0;
        c += (q.y < kk || (q.y == kk && j+1 < gown)) ? 1 : 0;
        c += (q.z < kk || (q.z == kk && j+2 < gown)) ? 1 : 0;
        c += (q.w < kk || (q.w == kk && j+3 < gown)) ? 1 : 0;
    }
    cnt[part][lane] = c;
    __syncthreads();
    if (part == 0) {
        int rank = 0;
        #pragma unroll
        for (int e = 0; e < 8; ++e) rank += cnt[e][lane];
        ((float4*)(ws + WS_SA))[rank] = A;
        ((float4*)(ws + WS_SB))[rank] = B;
        ((float4*)(ws + WS_SC))[rank] = make_float4(A.x, A.y, B.z, B.w);
        ((int*)  (ws + WS_SG))[rank] = gown;
    }
}

// ---- K2b: per-tile cull, ONCE.  256 blocks x 512 thr.  Order-preserving
// compaction of the globally z-sorted list into ws (list + count). ---------
__global__ __launch_bounds__(512) void cull_tile_kernel(float* __restrict__ ws)
{
    __shared__ int s_wcnt[8];
    const int tid  = threadIdx.x;
    const int lane = tid & 63;
    const int w    = tid >> 6;
    const int tile = blockIdx.x;
    const int tx = (tile & 15) * 8, ty = (tile >> 4) * 8;
    const float cxt = tx + 4.0f, cyt = ty + 4.0f;

    const float4* sA = (const float4*)(ws + WS_SA);
    const float4* sB = (const float4*)(ws + WS_SB);
    const float4* sC = (const float4*)(ws + WS_SC);
    const int*    sG = (const int*)  (ws + WS_SG);
    float4* tp = (float4*)(ws + WS_TPRM + (size_t)tile * CAP * 8);

    int Lrun = 0;
    #pragma unroll
    for (int ch = 0; ch < NG/RTH; ++ch) {
        const int j = ch*RTH + tid;
        float4 C = sC[j];
        bool sel = (fabsf(C.x - cxt) <= C.z + 3.5f) && (fabsf(C.y - cyt) <= C.w + 3.5f);
        unsigned long long m = __ballot(sel);
        if (lane == 0) s_wcnt[w] = (int)__popcll(m);
        __syncthreads();
        int pre = 0, tot = 0;
        #pragma unroll
        for (int e = 0; e < 8; ++e) { int cw = s_wcnt[e]; pre += (e < w) ? cw : 0; tot += cw; }
        if (sel) {
            int pos = Lrun + pre + (int)__popcll(m & ((1ull << lane) - 1ull));
            if (pos < CAP) {
                float4 Aa = sA[j], Bb = sB[j];
                tp[pos*2]   = Aa;
                tp[pos*2+1] = make_float4(Bb.x, Bb.y, __int_as_float(sG[j]), 0.f);
            }
        }
        Lrun += tot;
        __syncthreads();   // s_wcnt reuse
    }
    if (tid == 0) ((int*)(ws + WS_TCNT))[tile] = (Lrun < CAP) ? Lrun : CAP;
}

// ---- K3: raster. grid = NTILES*NSEG*NFB = 1024; block = 512 thr = 8 waves -
// bid -> tile = bid>>2 (tile's 4 blocks CONSECUTIVE -> different CUs),
// k = bid&3: seg = k>>1 (z-segment), fb = k&1 (32-feature block).
// Wave w composites z-slice v = seg*8+w, features fb*32..+31, acc[32]
// (proven 52-VGPR shape).  Colors via readfirstlane (uniform -> scalar).
__global__ __launch_bounds__(RTH) void raster_kernel(
    const float* __restrict__ colors, float* __restrict__ ws,
    float* __restrict__ out)
{
    __shared__ float ureg[CAP*8];        // staged prm list; epilogue overlays
    __shared__ float Tlds[ZSL*64];

    const int tid  = threadIdx.x;
    const int lane = tid & 63;
    const int w    = tid >> 6;           // wave 0..7 = z-slice within segment
    const int b    = blockIdx.x;
    const int tile = b >> 2;
    const int k    = b & 3;
    const int seg  = k >> 1;
    const int fb   = k & 1;
    const int tx = (tile & 15) * 8, ty = (tile >> 4) * 8;
    const float px = tx + (lane & 7) + 0.5f;
    const float py = ty + (lane >> 3) + 0.5f;

    float4* prm4 = (float4*)ureg;
    const int L = ((const int*)(ws + WS_TCNT))[tile];
    {   // coalesced copy of compacted list -> LDS (2L float4s)
        const float4* tp = (const float4*)(ws + WS_TPRM + (size_t)tile * CAP * 8);
        for (int i = tid; i < 2*L; i += RTH) prm4[i] = tp[i];
    }
    __syncthreads();

    // ---- composite: slice v = seg*8 + w, rows [v*L/16, (v+1)*L/16)
    float acc[32];
    #pragma unroll
    for (int i = 0; i < 32; ++i) acc[i] = 0.f;
    float T = 1.0f;
    {
        const int v  = seg * ZSL + w;
        const int r0 = (v * L) >> 4;
        const int r1 = ((v + 1) * L) >> 4;
        const float4* cph = (const float4*)colors + fb * 8;
        if (r1 > r0) {
            float4 e0 = prm4[2*r0], e1 = prm4[2*r0+1];
            for (int r = r0; r < r1; ++r) {
                // colors for CURRENT row: index is wave-uniform (broadcast
                // from LDS) -> readfirstlane proves it -> scalar-load path.
                const int gi = __builtin_amdgcn_readfirstlane(__float_as_int(e1.z));
                const float4* crow = cph + (size_t)(unsigned)gi * (DF/4);
                float4 c0 = crow[0], c1 = crow[1], c2 = crow[2], c3 = crow[3];
                float4 c4 = crow[4], c5 = crow[5], c6 = crow[6], c7 = crow[7];

                const int rn = (r + 1 < r1) ? r + 1 : r;
                float4 n0 = prm4[2*rn], n1 = prm4[2*rn+1];   // prefetch next params

                float dx = px - e0.x, dy = py - e0.y;
                float sig = 0.5f*(e0.z*dx*dx + e1.x*dy*dy) + e0.w*dx*dy;
                float al = fminf(e1.y * __expf(-sig), P_AMAX);
                al = (sig >= 0.f && al >= P_AMIN) ? al : 0.f;

                if (__ballot(al > 0.f)) {
                    float wv = T * al;
                    acc[0]  = fmaf(wv, c0.x, acc[0]);  acc[1]  = fmaf(wv, c0.y, acc[1]);
                    acc[2]  = fmaf(wv, c0.z, acc[2]);  acc[3]  = fmaf(wv, c0.w, acc[3]);
                    acc[4]  = fmaf(wv, c1.x, acc[4]);  acc[5]  = fmaf(wv, c1.y, acc[5]);
                    acc[6]  = fmaf(wv, c1.z, acc[6]);  acc[7]  = fmaf(wv, c1.w, acc[7]);
                    acc[8]  = fmaf(wv, c2.x, acc[8]);  acc[9]  = fmaf(wv, c2.y, acc[9]);
                    acc[10] = fmaf(wv, c2.z, acc[10]); acc[11] = fmaf(wv, c2.w, acc[11]);
                    acc[12] = fmaf(wv, c3.x, acc[12]); acc[13] = fmaf(wv, c3.y, acc[13]);
                    acc[14] = fmaf(wv, c3.z, acc[14]); acc[15] = fmaf(wv, c3.w, acc[15]);
                    acc[16] = fmaf(wv, c4.x, acc[16]); acc[17] = fmaf(wv, c4.y, acc[17]);
                    acc[18] = fmaf(wv, c4.z, acc[18]); acc[19] = fmaf(wv, c4.w, acc[19]);
                    acc[20] = fmaf(wv, c5.x, acc[20]); acc[21] = fmaf(wv, c5.y, acc[21]);
                    acc[22] = fmaf(wv, c5.z, acc[22]); acc[23] = fmaf(wv, c5.w, acc[23]);
                    acc[24] = fmaf(wv, c6.x, acc[24]); acc[25] = fmaf(wv, c6.y, acc[25]);
                    acc[26] = fmaf(wv, c6.z, acc[26]); acc[27] = fmaf(wv, c6.w, acc[27]);
                    acc[28] = fmaf(wv, c7.x, acc[28]); acc[29] = fmaf(wv, c7.y, acc[29]);
                    acc[30] = fmaf(wv, c7.z, acc[30]); acc[31] = fmaf(wv, c7.w, acc[31]);
                    T *= (1.f - al);
                    if (!__ballot(T >= 1e-6f)) break;   // whole wave saturated
                }
                e0 = n0; e1 = n1;
            }
        }
    }

    // ---- stage T; the barrier also ends prm reads before staging overlay
    Tlds[w*64 + lane] = T;
    __syncthreads();

    if (seg == 0 && fb == 0 && tid < 64) {
        float tp = 1.f;
        #pragma unroll
        for (int s = 0; s < ZSL; ++s) tp *= Tlds[s*64 + tid];
        ws[WS_T0 + tile*64 + tid] = tp;
    }

    // ---- 8 passes x 4 features: stage slice accs + affine combine + store.
    // Stage row = w*64+lane (512 rows, stride EST=12; max idx 6136 < 8192).
    #pragma unroll
    for (int pass = 0; pass < 8; ++pass) {
        float* ab = ureg + (w*64 + lane) * EST;
        *(float4*)ab = make_float4(acc[pass*4+0], acc[pass*4+1], acc[pass*4+2], acc[pass*4+3]);
        __syncthreads();
        if (tid < 256) {
            const int p = tid >> 2, c = tid & 3;     // pixel 0..63, feat-in-pass
            float r = ureg[((ZSL-1)*64 + p)*EST + c];
            #pragma unroll
            for (int s = ZSL-2; s >= 0; --s)
                r = fmaf(Tlds[s*64 + p], r, ureg[(s*64 + p)*EST + c]);
            const int pxg = tx + (p & 7), pyg = ty + (p >> 3);
            const int fi = fb*32 + pass*4 + c;
            if (seg == 0) out[(size_t)(pyg*IW + pxg)*DF + fi] = r;
            else          ws[WS_ACC1 + ((size_t)tile*64 + p)*DF + fi] = r;
        }
        __syncthreads();
    }
}

// ---- K4: out = A0 + T0 * A1 ----------------------------------------------
__global__ __launch_bounds__(1024) void combine_kernel(
    float* __restrict__ out, const float* __restrict__ ws)
{
    const int tile = blockIdx.x;
    const int p  = threadIdx.x >> 4;
    const int f0 = (threadIdx.x & 15) * 4;
    const int pxg = (tile & 15)*8 + (p & 7);
    const int pyg = (tile >> 4)*8 + (p >> 3);
    const float T0 = ws[WS_T0 + tile*64 + p];
    const float4 a1 = *(const float4*)(ws + WS_ACC1 + ((size_t)tile*64 + p)*DF + f0);
    float4* o = (float4*)(out + (size_t)(pyg*IW + pxg)*DF + f0);
    float4 v = *o;
    v.x = fmaf(T0, a1.x, v.x);
    v.y = fmaf(T0, a1.y, v.y);
    v.z = fmaf(T0, a1.z, v.z);
    v.w = fmaf(T0, a1.w, v.w);
    *o = v;
}

// ---------------------------------------------------------------------------
extern "C" void kernel_launch(void* const* d_in, const int* in_sizes, int n_in,
                              void* d_out, int out_size, void* d_ws, size_t ws_size,
                              hipStream_t stream) {
    const float* means  = (const float*)d_in[0];
    const float* quats  = (const float*)d_in[1];
    const float* scales = (const float*)d_in[2];
    const float* opac   = (const float*)d_in[3];
    const float* colors = (const float*)d_in[4];
    const float* c2o    = (const float*)d_in[5];
    const float* Kmat   = (const float*)d_in[6];
    float* out = (float*)d_out;

    if (ws_size >= WS_TOTAL * sizeof(float)) {
        float* ws = (float*)d_ws;
        prep_sort_kernel   <<<NG/64,              512, 0, stream>>>(means, quats, scales, opac, c2o, Kmat, ws);
        cull_tile_kernel   <<<NTILES,             512, 0, stream>>>(ws);
        raster_kernel      <<<NTILES*NSEG*NFB,    RTH, 0, stream>>>(colors, ws, out);
        combine_kernel     <<<NTILES,             1024,0, stream>>>(out, ws);
    } else {
        // fallback: legacy fused single-kernel path
        (void)hipFuncSetAttribute((const void*)fused_render_kernel,
                                  hipFuncAttributeMaxDynamicSharedMemorySize,
                                  L_TOTAL * 4);
        fused_render_kernel<<<IH*IW/64, RB, L_TOTAL*4, stream>>>(
            means, quats, scales, opac, colors, c2o, Kmat, out);
    }
}

// Round 7
// 104.211 us; speedup vs baseline: 1.2251x; 1.0575x over previous
//
#include <hip/hip_runtime.h>

constexpr int NG  = 2048;   // gaussians
constexpr int DF  = 64;     // feature dim
constexpr int IW  = 128;
constexpr int IH  = 128;

#define P_NEAR 0.01f
#define P_BLUR 0.3f
#define P_AMIN (1.0f/255.0f)
#define P_AMAX 0.999f

// ---------------------------------------------------------------------------
__device__ inline void invert4x4(const float* m, float* inv) {
    inv[0]  =  m[5]*m[10]*m[15] - m[5]*m[11]*m[14] - m[9]*m[6]*m[15] + m[9]*m[7]*m[14] + m[13]*m[6]*m[11] - m[13]*m[7]*m[10];
    inv[4]  = -m[4]*m[10]*m[15] + m[4]*m[11]*m[14] + m[8]*m[6]*m[15] - m[8]*m[7]*m[14] - m[12]*m[6]*m[11] + m[12]*m[7]*m[10];
    inv[8]  =  m[4]*m[9]*m[15]  - m[4]*m[11]*m[13] - m[8]*m[5]*m[15] + m[8]*m[7]*m[13] + m[12]*m[5]*m[11] - m[12]*m[7]*m[9];
    inv[12] = -m[4]*m[9]*m[14]  + m[4]*m[10]*m[13] + m[8]*m[5]*m[14] - m[8]*m[6]*m[13] - m[12]*m[5]*m[10] + m[12]*m[6]*m[9];
    inv[1]  = -m[1]*m[10]*m[15] + m[1]*m[11]*m[14] + m[9]*m[2]*m[15] - m[9]*m[3]*m[14] - m[13]*m[2]*m[11] + m[13]*m[3]*m[10];
    inv[5]  =  m[0]*m[10]*m[15] - m[0]*m[11]*m[14] - m[8]*m[2]*m[15] + m[8]*m[3]*m[14] + m[12]*m[2]*m[11] - m[12]*m[3]*m[10];
    inv[9]  = -m[0]*m[9]*m[15]  + m[0]*m[11]*m[13] + m[8]*m[1]*m[15] - m[8]*m[3]*m[13] - m[12]*m[1]*m[11] + m[12]*m[3]*m[9];
    inv[13] =  m[0]*m[9]*m[14]  - m[0]*m[10]*m[13] - m[8]*m[1]*m[14] + m[8]*m[2]*m[13] + m[12]*m[1]*m[10] - m[12]*m[2]*m[9];
    inv[2]  =  m[1]*m[6]*m[15]  - m[1]*m[7]*m[14]  - m[5]*m[2]*m[15] + m[5]*m[3]*m[14] + m[13]*m[2]*m[7]  - m[13]*m[3]*m[6];
    inv[6]  = -m[0]*m[6]*m[15]  + m[0]*m[7]*m[14]  + m[4]*m[2]*m[15] - m[4]*m[3]*m[14] - m[12]*m[2]*m[7]  + m[12]*m[3]*m[6];
    inv[10] =  m[0]*m[5]*m[15]  - m[0]*m[7]*m[13]  - m[4]*m[1]*m[15] + m[4]*m[3]*m[13] + m[12]*m[1]*m[7]  - m[12]*m[3]*m[5];
    inv[14] = -m[0]*m[5]*m[14]  + m[0]*m[6]*m[13]  + m[4]*m[1]*m[14] - m[4]*m[2]*m[13] - m[12]*m[1]*m[6]  + m[12]*m[2]*m[5];
    inv[3]  = -m[1]*m[6]*m[11]  + m[1]*m[7]*m[10]  + m[5]*m[2]*m[11] - m[5]*m[3]*m[10] - m[9]*m[2]*m[7]   + m[9]*m[3]*m[6];
    inv[7]  =  m[0]*m[6]*m[11]  - m[0]*m[7]*m[10]  - m[4]*m[2]*m[11] + m[4]*m[3]*m[10] + m[8]*m[2]*m[7]   - m[8]*m[3]*m[6];
    inv[11] = -m[0]*m[5]*m[11]  + m[0]*m[7]*m[9]   + m[4]*m[1]*m[11] - m[4]*m[3]*m[9]  - m[8]*m[1]*m[7]   + m[8]*m[3]*m[5];
    inv[15] =  m[0]*m[5]*m[10]  - m[0]*m[6]*m[9]   - m[4]*m[1]*m[10] + m[4]*m[2]*m[9]  + m[8]*m[1]*m[6]   - m[8]*m[2]*m[5];
    float det = m[0]*inv[0] + m[1]*inv[4] + m[2]*inv[8] + m[3]*inv[12];
    det = 1.0f / det;
    #pragma unroll
    for (int i = 0; i < 16; ++i) inv[i] *= det;
}

// ===========================================================================
// LEGACY single-kernel path (fallback when workspace is too small)
// ===========================================================================
constexpr int NZ  = 8;
constexpr int RB  = 1024;
constexpr int CAP = 1024;

constexpr int L_T    = 0;
constexpr int L_CNT  = 512;
constexpr int L_SIDX = 528;
constexpr int L_OVL  = L_SIDX + CAP;
constexpr int L_PRM  = L_OVL;
constexpr int L_KEYS = L_PRM + CAP * 8;
constexpr int L_ACC  = L_OVL;
constexpr int ACC_ST = 66;
constexpr int L_TOTAL = L_OVL + NZ * 64 * ACC_ST;

__global__ __launch_bounds__(RB, 4) void fused_render_kernel(
    const float* __restrict__ means,  const float* __restrict__ quats,
    const float* __restrict__ scales, const float* __restrict__ opac_logits,
    const float* __restrict__ colors, const float* __restrict__ c2o,
    const float* __restrict__ Kmat,   float* __restrict__ out)
{
    extern __shared__ float lds[];
    int*                cnt  = (int*)(lds + L_CNT);
    int*                sidx = (int*)(lds + L_SIDX);
    unsigned long long* keys = (unsigned long long*)(lds + L_KEYS);
    float4*             prm4 = (float4*)(lds + L_PRM);

    const int tid  = threadIdx.x;
    const int lane = tid & 63;
    const int wv16 = tid >> 6;
    const int sz   = wv16 >> 1;
    const int hh   = wv16 & 1;
    const int tile = blockIdx.x;
    const int tx = (tile & 15) * 8;
    const int ty = (tile >> 4) * 8;
    const float px = tx + (lane & 7) + 0.5f;
    const float py = ty + (lane >> 3) + 0.5f;
    const float cxt = tx + 4.0f, cyt = ty + 4.0f;

    if (tid == 0) *cnt = 0;
    __syncthreads();

    {
        float inv[16];
        {
            float m[16];
            #pragma unroll
            for (int t = 0; t < 16; ++t) m[t] = c2o[t];
            invert4x4(m, inv);
        }
        const float fx = Kmat[0], fy = Kmat[4], cx = Kmat[2], cy = Kmat[5];

        #pragma unroll
        for (int c = 0; c < NG / RB; ++c) {
            const int g = c * RB + tid;
            float mx = means[g*3+0], my = means[g*3+1], mz = means[g*3+2];
            float X = inv[0]*mx + inv[1]*my + inv[2]*mz  + inv[3];
            float Y = inv[4]*mx + inv[5]*my + inv[6]*mz  + inv[7];
            float Z = inv[8]*mx + inv[9]*my + inv[10]*mz + inv[11];

            float qw = quats[g*4+0], qx = quats[g*4+1], qy = quats[g*4+2], qz = quats[g*4+3];
            float qn = rsqrtf(qw*qw + qx*qx + qy*qy + qz*qz);
            qw *= qn; qx *= qn; qy *= qn; qz *= qn;
            float R00 = 1.f - 2.f*(qy*qy + qz*qz), R01 = 2.f*(qx*qy - qw*qz), R02 = 2.f*(qx*qz + qw*qy);
            float R10 = 2.f*(qx*qy + qw*qz), R11 = 1.f - 2.f*(qx*qx + qz*qz), R12 = 2.f*(qy*qz - qw*qx);
            float R20 = 2.f*(qx*qz - qw*qy), R21 = 2.f*(qy*qz + qw*qx), R22 = 1.f - 2.f*(qx*qx + qy*qy);

            float s0 = expf(scales[g*3+0]), s1 = expf(scales[g*3+1]), s2 = expf(scales[g*3+2]);
            float M00 = R00*s0, M01 = R01*s1, M02 = R02*s2;
            float M10 = R10*s0, M11 = R11*s1, M12 = R12*s2;
            float M20 = R20*s0, M21 = R21*s1, M22 = R22*s2;

            float V00 = M00*M00 + M01*M01 + M02*M02;
            float V01 = M00*M10 + M01*M11 + M02*M12;
            float V02 = M00*M20 + M01*M21 + M02*M22;
            float V11 = M10*M10 + M11*M11 + M12*M12;
            float V12 = M10*M20 + M11*M21 + M12*M22;
            float V22 = M20*M20 + M21*M21 + M22*M22;

            float Rv[3][3] = {{inv[0],inv[1],inv[2]},{inv[4],inv[5],inv[6]},{inv[8],inv[9],inv[10]}};
            float Vm[3][3] = {{V00,V01,V02},{V01,V11,V12},{V02,V12,V22}};
            float Tm[3][3], C[3][3];
            #pragma unroll
            for (int r = 0; r < 3; ++r)
                #pragma unroll
                for (int cc = 0; cc < 3; ++cc)
                    Tm[r][cc] = Rv[r][0]*Vm[0][cc] + Rv[r][1]*Vm[1][cc] + Rv[r][2]*Vm[2][cc];
            #pragma unroll
            for (int r = 0; r < 3; ++r)
                #pragma unroll
                for (int cc = 0; cc < 3; ++cc)
                    C[r][cc] = Tm[r][0]*Rv[cc][0] + Tm[r][1]*Rv[cc][1] + Tm[r][2]*Rv[cc][2];

            float rz = 1.0f / Z;
            float j00 = fx*rz, j02 = -fx*X*rz*rz;
            float j11 = fy*rz, j12 = -fy*Y*rz*rz;

            float c00 = j00*j00*C[0][0] + 2.f*j00*j02*C[0][2] + j02*j02*C[2][2];
            float c01 = j00*j11*C[0][1] + j00*j12*C[0][2] + j02*j11*C[1][2] + j02*j12*C[2][2];
            float c11 = j11*j11*C[1][1] + 2.f*j11*j12*C[1][2] + j12*j12*C[2][2];

            float a = c00 + P_BLUR;
            float b = c01;
            float cc_ = c11 + P_BLUR;
            float det = a*cc_ - b*b;

            float pmx = fx*X*rz + cx;
            float pmy = fy*Y*rz + cy;

            float lam = 0.5f*(a + cc_) + sqrtf(fmaxf(0.25f*(a - cc_)*(a - cc_) + b*b, 1e-12f));
            float radius = 3.0f * sqrtf(lam);
            bool valid = (Z > P_NEAR) && (det > 0.0f) && (radius > 3.0f);

            float op = 1.0f / (1.0f + expf(-opac_logits[g]));

            bool sel = false;
            float cA = 0.f, cB = 0.f, cC2 = 0.f;
            if (valid) {
                float rdet = 1.0f / det;
                cA = cc_ * rdet; cB = -b * rdet; cC2 = a * rdet;
                float smax = logf(255.0f * op);
                if (smax > 0.f) {
                    float rx = sqrtf(2.f * a   * smax) * 1.0001f + 1e-3f;
                    float ry = sqrtf(2.f * cc_ * smax) * 1.0001f + 1e-3f;
                    sel = (fabsf(pmx - cxt) <= rx + 3.5f) && (fabsf(pmy - cyt) <= ry + 3.5f);
                }
            }

            unsigned long long m = __ballot(sel);
            int wbase = 0;
            if (lane == 0 && m) wbase = atomicAdd(cnt, (int)__popcll(m));
            wbase = __shfl(wbase, 0);
            if (sel) {
                int pos = wbase + (int)__popcll(m & ((1ull << lane) - 1ull));
                if (pos < CAP) {
                    prm4[pos*2]   = make_float4(pmx, pmy, cA, cB);
                    prm4[pos*2+1] = make_float4(cC2, op, __int_as_float(g), 0.f);
                    keys[pos] = ((unsigned long long)__float_as_uint(Z) << 32) | (unsigned)g;
                }
            }
        }
    }
    __syncthreads();
    int L = *cnt;
    if (L > CAP) L = CAP;

    {
        int padL = (L + 1) & ~1;
        if (tid < padL - L) keys[L + tid] = ~0ull;
        __syncthreads();
        const ulonglong2* k2 = (const ulonglong2*)keys;
        if (tid < L) {
            unsigned long long kk = keys[tid];
            int rank = 0;
            #pragma unroll 2
            for (int c = 0; c < padL / 2; ++c) {
                ulonglong2 q = k2[c];
                rank += (q.x < kk) + (q.y < kk);
            }
            sidx[rank] = tid;
        }
    }
    __syncthreads();

    float acc[32];
    #pragma unroll
    for (int f = 0; f < 32; ++f) acc[f] = 0.f;
    float T = 1.0f;

    {
        const int r0 = (sz * L) >> 3;
        const int r1 = ((sz + 1) * L) >> 3;
        const float4* cph = (const float4*)colors + hh * 8;
        if (r1 > r0) {
            int k = sidx[r0];
            float4 e0 = prm4[k*2], e1 = prm4[k*2+1];
            for (int r = r0; r < r1; ++r) {
                int kn = (r + 1 < r1) ? sidx[r + 1] : k;
                float4 n0 = prm4[kn*2], n1 = prm4[kn*2+1];

                float dx = px - e0.x, dy = py - e0.y;
                float sig = 0.5f*(e0.z*dx*dx + e1.x*dy*dy) + e0.w*dx*dy;
                float al = fminf(e1.y * __expf(-sig), P_AMAX);
                al = (sig >= 0.f && al >= P_AMIN) ? al : 0.f;

                if (__ballot(al > 0.f)) {
                    float wv = T * al;
                    const float4* crow = cph + (size_t)(unsigned)__float_as_int(e1.z) * 16;
                    #pragma unroll
                    for (int q = 0; q < 8; ++q) {
                        float4 cv = crow[q];
                        acc[4*q+0] = fmaf(wv, cv.x, acc[4*q+0]);
                        acc[4*q+1] = fmaf(wv, cv.y, acc[4*q+1]);
                        acc[4*q+2] = fmaf(wv, cv.z, acc[4*q+2]);
                        acc[4*q+3] = fmaf(wv, cv.w, acc[4*q+3]);
                    }
                    T *= (1.f - al);
                    if (!__ballot(T >= 1e-6f)) break;
                }
                e0 = n0; e1 = n1; k = kn;
            }
        }
    }

    if (hh == 0) lds[L_T + sz*64 + lane] = T;
    __syncthreads();
    {
        float* ab = lds + L_ACC + (size_t)(sz * 64 + lane) * ACC_ST + hh * 32;
        #pragma unroll
        for (int q = 0; q < 16; ++q)
            *(float2*)(ab + 2*q) = make_float2(acc[2*q], acc[2*q+1]);
    }
    __syncthreads();

    {
        int p  = tid >> 4;
        int f0 = (tid & 15) * 4;
        float r0, r1, r2, r3;
        const float* ab = lds + L_ACC + (size_t)((NZ-1)*64 + p) * ACC_ST + f0;
        { float2 u = *(const float2*)ab, v = *(const float2*)(ab + 2);
          r0 = u.x; r1 = u.y; r2 = v.x; r3 = v.y; }
        #pragma unroll
        for (int s = NZ - 2; s >= 0; --s) {
            float Ts = lds[L_T + s*64 + p];
            const float* as_ = lds + L_ACC + (size_t)(s*64 + p) * ACC_ST + f0;
            float2 u = *(const float2*)as_, v = *(const float2*)(as_ + 2);
            r0 = fmaf(Ts, r0, u.x); r1 = fmaf(Ts, r1, u.y);
            r2 = fmaf(Ts, r2, v.x); r3 = fmaf(Ts, r3, v.y);
        }
        int pyg = ty + (p >> 3), pxg = tx + (p & 7);
        float* op_ = out + (size_t)(pyg * IW + pxg) * DF + f0;
        *(float4*)op_ = make_float4(r0, r1, r2, r3);
    }
}

// ===========================================================================
// 2-kernel pipeline (R7).
// R6 post-mortem: bench 110.2 (was 127.7); fills @41us fixed; overhead model
// calibrated: ~64us fixed harness + ~3.5us per extra launch.  Remaining
// kernels all < fill time.  R7 cuts launches 4 -> 2 and deletes the
// WS_TPRM/ACC1 round-trips: cull inlined into raster (only 2x duplication
// now, R4's verified pattern), NSEG=1 so the epilogue affine over all 8
// z-slices finishes the pixel completely -> no combine kernel.  Per-wave
// serial length doubles (L/8), but raster is throughput-bound (~19M
// wave-instrs) so the tail hides.
// ===========================================================================
constexpr int ZSL    = 8;     // z-slices per raster block (= waves per block)
constexpr int NFB    = 2;     // feature-blocks per tile (32 feats each)
constexpr int RTH    = 512;   // raster block threads
constexpr int NTILES = 256;
constexpr int EST    = 12;    // epilogue stage stride (floats), 16B-aligned

// workspace layout (float offsets) — ~106 KB total
constexpr size_t WS_SA   = 0;                       // sorted A {pmx,pmy,cA,cB}
constexpr size_t WS_SB   = WS_SA   + NG*4;          // sorted B {cC2,op,rx,ry}
constexpr size_t WS_SC   = WS_SB   + NG*4;          // sorted cull {pmx,pmy,rx,ry}
constexpr size_t WS_SG   = WS_SC   + NG*4;          // sorted gaussian idx
constexpr size_t WS_TOTAL= WS_SG   + NG;

// ---- K1: fused preprocess + global stable z-sort + scatter (R6, proven) ---
__global__ __launch_bounds__(512) void prep_sort_kernel(
    const float* __restrict__ means,  const float* __restrict__ quats,
    const float* __restrict__ scales, const float* __restrict__ opac_logits,
    const float* __restrict__ c2o,    const float* __restrict__ Kmat,
    float* __restrict__ ws)
{
    __shared__ __align__(16) unsigned zlds[NG];
    __shared__ int cnt[8][64];
    const int tid  = threadIdx.x;
    const int lane = tid & 63;
    const int part = tid >> 6;
    const int b    = blockIdx.x;
    const int gown = b * 64 + lane;

    float inv[16];
    {
        float m[16];
        #pragma unroll
        for (int t = 0; t < 16; ++t) m[t] = c2o[t];
        invert4x4(m, inv);
    }
    const float fx = Kmat[0], fy = Kmat[4], cx = Kmat[2], cy = Kmat[5];

    // ---- all 2048 z-keys (4 per thread), deterministic across blocks
    #pragma unroll
    for (int u = 0; u < NG/512; ++u) {
        const int g = u*512 + tid;
        float mx = means[g*3+0], my = means[g*3+1], mz = means[g*3+2];
        float Z = inv[8]*mx + inv[9]*my + inv[10]*mz + inv[11];
        zlds[g] = __float_as_uint(Z);   // Z>0 for contributors: uint order == float order
    }

    // ---- wave 0: full preprocess of own gaussian (registers)
    float4 A = make_float4(0.f,0.f,0.f,0.f);
    float4 B = make_float4(0.f,0.f,-1e9f,-1e9f);
    if (part == 0) {
        const int g = gown;
        float mx = means[g*3+0], my = means[g*3+1], mz = means[g*3+2];
        float X = inv[0]*mx + inv[1]*my + inv[2]*mz  + inv[3];
        float Y = inv[4]*mx + inv[5]*my + inv[6]*mz  + inv[7];
        float Z = inv[8]*mx + inv[9]*my + inv[10]*mz + inv[11];

        float qw = quats[g*4+0], qx = quats[g*4+1], qy = quats[g*4+2], qz = quats[g*4+3];
        float qn = rsqrtf(qw*qw + qx*qx + qy*qy + qz*qz);
        qw *= qn; qx *= qn; qy *= qn; qz *= qn;
        float R00 = 1.f - 2.f*(qy*qy + qz*qz), R01 = 2.f*(qx*qy - qw*qz), R02 = 2.f*(qx*qz + qw*qy);
        float R10 = 2.f*(qx*qy + qw*qz), R11 = 1.f - 2.f*(qx*qx + qz*qz), R12 = 2.f*(qy*qz - qw*qx);
        float R20 = 2.f*(qx*qz - qw*qy), R21 = 2.f*(qy*qz + qw*qx), R22 = 1.f - 2.f*(qx*qx + qy*qy);

        float s0 = expf(scales[g*3+0]), s1 = expf(scales[g*3+1]), s2 = expf(scales[g*3+2]);
        float M00 = R00*s0, M01 = R01*s1, M02 = R02*s2;
        float M10 = R10*s0, M11 = R11*s1, M12 = R12*s2;
        float M20 = R20*s0, M21 = R21*s1, M22 = R22*s2;

        float V00 = M00*M00 + M01*M01 + M02*M02;
        float V01 = M00*M10 + M01*M11 + M02*M12;
        float V02 = M00*M20 + M01*M21 + M02*M22;
        float V11 = M10*M10 + M11*M11 + M12*M12;
        float V12 = M10*M20 + M11*M21 + M12*M22;
        float V22 = M20*M20 + M21*M21 + M22*M22;

        float Rv[3][3] = {{inv[0],inv[1],inv[2]},{inv[4],inv[5],inv[6]},{inv[8],inv[9],inv[10]}};
        float Vm[3][3] = {{V00,V01,V02},{V01,V11,V12},{V02,V12,V22}};
        float Tm[3][3], C[3][3];
        #pragma unroll
        for (int r = 0; r < 3; ++r)
            #pragma unroll
            for (int cc = 0; cc < 3; ++cc)
                Tm[r][cc] = Rv[r][0]*Vm[0][cc] + Rv[r][1]*Vm[1][cc] + Rv[r][2]*Vm[2][cc];
        #pragma unroll
        for (int r = 0; r < 3; ++r)
            #pragma unroll
            for (int cc = 0; cc < 3; ++cc)
                C[r][cc] = Tm[r][0]*Rv[cc][0] + Tm[r][1]*Rv[cc][1] + Tm[r][2]*Rv[cc][2];

        float rz = 1.0f / Z;
        float j00 = fx*rz, j02 = -fx*X*rz*rz;
        float j11 = fy*rz, j12 = -fy*Y*rz*rz;

        float c00 = j00*j00*C[0][0] + 2.f*j00*j02*C[0][2] + j02*j02*C[2][2];
        float c01 = j00*j11*C[0][1] + j00*j12*C[0][2] + j02*j11*C[1][2] + j02*j12*C[2][2];
        float c11 = j11*j11*C[1][1] + 2.f*j11*j12*C[1][2] + j12*j12*C[2][2];

        float a = c00 + P_BLUR;
        float bb = c01;
        float cc_ = c11 + P_BLUR;
        float det = a*cc_ - bb*bb;

        float pmx = fx*X*rz + cx;
        float pmy = fy*Y*rz + cy;

        float lam = 0.5f*(a + cc_) + sqrtf(fmaxf(0.25f*(a - cc_)*(a - cc_) + bb*bb, 1e-12f));
        float radius = 3.0f * sqrtf(lam);
        bool valid = (Z > P_NEAR) && (det > 0.0f) && (radius > 3.0f);

        float op = 1.0f / (1.0f + expf(-opac_logits[g]));

        float cA = 0.f, cB = 0.f, cC2 = 0.f, rx = -1e9f, ry = -1e9f;
        if (valid) {
            float rdet = 1.0f / det;
            cA = cc_ * rdet; cB = -bb * rdet; cC2 = a * rdet;
            float smax = logf(255.0f * op);
            if (smax > 0.f) {
                rx = sqrtf(2.f * a   * smax) * 1.0001f + 1e-3f;
                ry = sqrtf(2.f * cc_ * smax) * 1.0001f + 1e-3f;
            }
        }
        A = make_float4(pmx, pmy, cA, cB);
        B = make_float4(cC2, op, rx, ry);
    }
    __syncthreads();

    // ---- rank own 64 gaussians against all 2048 (z,idx) keys
    const unsigned kk = zlds[b*64 + lane];
    const uint4* zl4 = (const uint4*)zlds;
    int c = 0;
    #pragma unroll 4
    for (int i = part*64; i < part*64 + 64; ++i) {
        uint4 q = zl4[i];
        const int j = i * 4;
        c += (q.x < kk || (q.x == kk && j+0 < gown)) ? 1 : 0;
        c += (q.y < kk || (q.y == kk && j+1 < gown)) ? 1 : 0;
        c += (q.z < kk || (q.z == kk && j+2 < gown)) ? 1 : 0;
        c += (q.w < kk || (q.w == kk && j+3 < gown)) ? 1 : 0;
    }
    cnt[part][lane] = c;
    __syncthreads();
    if (part == 0) {
        int rank = 0;
        #pragma unroll
        for (int e = 0; e < 8; ++e) rank += cnt[e][lane];
        ((float4*)(ws + WS_SA))[rank] = A;
        ((float4*)(ws + WS_SB))[rank] = B;
        ((float4*)(ws + WS_SC))[rank] = make_float4(A.x, A.y, B.z, B.w);
        ((int*)  (ws + WS_SG))[rank] = gown;
    }
}

// ---- K2: raster. grid = NTILES*NFB = 512; block = 512 thr = 8 waves ------
// bid -> tile = bid>>1 (tile's 2 blocks CONSECUTIVE -> different CUs),
// fb = bid&1 (32-feature block).  Inline cull (order-preserving compaction
// of the globally z-sorted list into LDS), then wave w composites z-slice w
// (rows [w*L/8,(w+1)*L/8), features fb*32..+31, acc[32]), then the epilogue
// affine-combines all 8 slices and writes out directly.  No combine kernel.
__global__ __launch_bounds__(RTH) void raster_kernel(
    const float* __restrict__ colors, float* __restrict__ ws,
    float* __restrict__ out)
{
    __shared__ float ureg[CAP*8];        // culled prm list; epilogue overlays
    __shared__ float Tlds[ZSL*64];
    __shared__ int   s_wcnt[8];

    const int tid  = threadIdx.x;
    const int lane = tid & 63;
    const int w    = tid >> 6;           // wave 0..7 = z-slice
    const int b    = blockIdx.x;
    const int tile = b >> 1;
    const int fb   = b & 1;
    const int tx = (tile & 15) * 8, ty = (tile >> 4) * 8;
    const float px = tx + (lane & 7) + 0.5f;
    const float py = ty + (lane >> 3) + 0.5f;
    const float cxt = tx + 4.0f, cyt = ty + 4.0f;

    float4* prm4 = (float4*)ureg;
    const float4* sA = (const float4*)(ws + WS_SA);
    const float4* sB = (const float4*)(ws + WS_SB);
    const float4* sC = (const float4*)(ws + WS_SC);
    const int*    sG = (const int*)  (ws + WS_SG);

    // ---- inline cull: order-preserving compaction of the z-sorted list
    int Lrun = 0;
    #pragma unroll
    for (int ch = 0; ch < NG/RTH; ++ch) {
        const int j = ch*RTH + tid;
        float4 C = sC[j];
        bool sel = (fabsf(C.x - cxt) <= C.z + 3.5f) && (fabsf(C.y - cyt) <= C.w + 3.5f);
        unsigned long long m = __ballot(sel);
        if (lane == 0) s_wcnt[w] = (int)__popcll(m);
        __syncthreads();
        int pre = 0, tot = 0;
        #pragma unroll
        for (int e = 0; e < 8; ++e) { int cw = s_wcnt[e]; pre += (e < w) ? cw : 0; tot += cw; }
        if (sel) {
            int pos = Lrun + pre + (int)__popcll(m & ((1ull << lane) - 1ull));
            if (pos < CAP) {
                float4 Aa = sA[j], Bb = sB[j];
                prm4[pos*2]   = Aa;
                prm4[pos*2+1] = make_float4(Bb.x, Bb.y, __int_as_float(sG[j]), 0.f);
            }
        }
        Lrun += tot;
        __syncthreads();   // s_wcnt reuse + prm visibility
    }
    const int L = (Lrun < CAP) ? Lrun : CAP;

    // ---- composite: slice w, rows [w*L/8, (w+1)*L/8)
    float acc[32];
    #pragma unroll
    for (int i = 0; i < 32; ++i) acc[i] = 0.f;
    float T = 1.0f;
    {
        const int r0 = (w * L) >> 3;
        const int r1 = ((w + 1) * L) >> 3;
        const float4* cph = (const float4*)colors + fb * 8;
        if (r1 > r0) {
            float4 e0 = prm4[2*r0], e1 = prm4[2*r0+1];
            for (int r = r0; r < r1; ++r) {
                // colors for CURRENT row: index is wave-uniform (broadcast
                // from LDS) -> readfirstlane proves it -> scalar-load path.
                const int gi = __builtin_amdgcn_readfirstlane(__float_as_int(e1.z));
                const float4* crow = cph + (size_t)(unsigned)gi * (DF/4);
                float4 c0 = crow[0], c1 = crow[1], c2 = crow[2], c3 = crow[3];
                float4 c4 = crow[4], c5 = crow[5], c6 = crow[6], c7 = crow[7];

                const int rn = (r + 1 < r1) ? r + 1 : r;
                float4 n0 = prm4[2*rn], n1 = prm4[2*rn+1];   // prefetch next params

                float dx = px - e0.x, dy = py - e0.y;
                float sig = 0.5f*(e0.z*dx*dx + e1.x*dy*dy) + e0.w*dx*dy;
                float al = fminf(e1.y * __expf(-sig), P_AMAX);
                al = (sig >= 0.f && al >= P_AMIN) ? al : 0.f;

                if (__ballot(al > 0.f)) {
                    float wv = T * al;
                    acc[0]  = fmaf(wv, c0.x, acc[0]);  acc[1]  = fmaf(wv, c0.y, acc[1]);
                    acc[2]  = fmaf(wv, c0.z, acc[2]);  acc[3]  = fmaf(wv, c0.w, acc[3]);
                    acc[4]  = fmaf(wv, c1.x, acc[4]);  acc[5]  = fmaf(wv, c1.y, acc[5]);
                    acc[6]  = fmaf(wv, c1.z, acc[6]);  acc[7]  = fmaf(wv, c1.w, acc[7]);
                    acc[8]  = fmaf(wv, c2.x, acc[8]);  acc[9]  = fmaf(wv, c2.y, acc[9]);
                    acc[10] = fmaf(wv, c2.z, acc[10]); acc[11] = fmaf(wv, c2.w, acc[11]);
                    acc[12] = fmaf(wv, c3.x, acc[12]); acc[13] = fmaf(wv, c3.y, acc[13]);
                    acc[14] = fmaf(wv, c3.z, acc[14]); acc[15] = fmaf(wv, c3.w, acc[15]);
                    acc[16] = fmaf(wv, c4.x, acc[16]); acc[17] = fmaf(wv, c4.y, acc[17]);
                    acc[18] = fmaf(wv, c4.z, acc[18]); acc[19] = fmaf(wv, c4.w, acc[19]);
                    acc[20] = fmaf(wv, c5.x, acc[20]); acc[21] = fmaf(wv, c5.y, acc[21]);
                    acc[22] = fmaf(wv, c5.z, acc[22]); acc[23] = fmaf(wv, c5.w, acc[23]);
                    acc[24] = fmaf(wv, c6.x, acc[24]); acc[25] = fmaf(wv, c6.y, acc[25]);
                    acc[26] = fmaf(wv, c6.z, acc[26]); acc[27] = fmaf(wv, c6.w, acc[27]);
                    acc[28] = fmaf(wv, c7.x, acc[28]); acc[29] = fmaf(wv, c7.y, acc[29]);
                    acc[30] = fmaf(wv, c7.z, acc[30]); acc[31] = fmaf(wv, c7.w, acc[31]);
                    T *= (1.f - al);
                    if (!__ballot(T >= 1e-6f)) break;   // whole wave saturated
                }
                e0 = n0; e1 = n1;
            }
        }
    }

    // ---- stage T; barrier also ends prm reads before the staging overlay
    Tlds[w*64 + lane] = T;
    __syncthreads();

    // ---- 8 passes x 4 features: stage slice accs + affine combine + store.
    // out = a0 + T0*(a1 + T1*(...)): complete per pixel-feature, no combine.
    // Stage row = w*64+lane (512 rows, stride EST=12; max idx 6136 < 8192).
    #pragma unroll
    for (int pass = 0; pass < 8; ++pass) {
        float* ab = ureg + (w*64 + lane) * EST;
        *(float4*)ab = make_float4(acc[pass*4+0], acc[pass*4+1], acc[pass*4+2], acc[pass*4+3]);
        __syncthreads();
        if (tid < 256) {
            const int p = tid >> 2, c = tid & 3;     // pixel 0..63, feat-in-pass
            float r = ureg[((ZSL-1)*64 + p)*EST + c];
            #pragma unroll
            for (int s = ZSL-2; s >= 0; --s)
                r = fmaf(Tlds[s*64 + p], r, ureg[(s*64 + p)*EST + c]);
            const int pxg = tx + (p & 7), pyg = ty + (p >> 3);
            const int fi = fb*32 + pass*4 + c;
            out[(size_t)(pyg*IW + pxg)*DF + fi] = r;
        }
        __syncthreads();
    }
}

// ---------------------------------------------------------------------------
extern "C" void kernel_launch(void* const* d_in, const int* in_sizes, int n_in,
                              void* d_out, int out_size, void* d_ws, size_t ws_size,
                              hipStream_t stream) {
    const float* means  = (const float*)d_in[0];
    const float* quats  = (const float*)d_in[1];
    const float* scales = (const float*)d_in[2];
    const float* opac   = (const float*)d_in[3];
    const float* colors = (const float*)d_in[4];
    const float* c2o    = (const float*)d_in[5];
    const float* Kmat   = (const float*)d_in[6];
    float* out = (float*)d_out;

    if (ws_size >= WS_TOTAL * sizeof(float)) {
        float* ws = (float*)d_ws;
        prep_sort_kernel<<<NG/64,        512, 0, stream>>>(means, quats, scales, opac, c2o, Kmat, ws);
        raster_kernel   <<<NTILES*NFB,   RTH, 0, stream>>>(colors, ws, out);
    } else {
        // fallback: legacy fused single-kernel path
        (void)hipFuncSetAttribute((const void*)fused_render_kernel,
                                  hipFuncAttributeMaxDynamicSharedMemorySize,
                                  L_TOTAL * 4);
        fused_render_kernel<<<IH*IW/64, RB, L_TOTAL*4, stream>>>(
            means, quats, scales, opac, colors, c2o, Kmat, out);
    }
}

// Round 8
// 100.364 us; speedup vs baseline: 1.2721x; 1.0383x over previous
//
#include <hip/hip_runtime.h>

constexpr int NG  = 2048;   // gaussians
constexpr int DF  = 64;     // feature dim
constexpr int IW  = 128;
constexpr int IH  = 128;

#define P_NEAR 0.01f
#define P_BLUR 0.3f
#define P_AMIN (1.0f/255.0f)
#define P_AMAX 0.999f

// ---------------------------------------------------------------------------
__device__ inline void invert4x4(const float* m, float* inv) {
    inv[0]  =  m[5]*m[10]*m[15] - m[5]*m[11]*m[14] - m[9]*m[6]*m[15] + m[9]*m[7]*m[14] + m[13]*m[6]*m[11] - m[13]*m[7]*m[10];
    inv[4]  = -m[4]*m[10]*m[15] + m[4]*m[11]*m[14] + m[8]*m[6]*m[15] - m[8]*m[7]*m[14] - m[12]*m[6]*m[11] + m[12]*m[7]*m[10];
    inv[8]  =  m[4]*m[9]*m[15]  - m[4]*m[11]*m[13] - m[8]*m[5]*m[15] + m[8]*m[7]*m[13] + m[12]*m[5]*m[11] - m[12]*m[7]*m[9];
    inv[12] = -m[4]*m[9]*m[14]  + m[4]*m[10]*m[13] + m[8]*m[5]*m[14] - m[8]*m[6]*m[13] - m[12]*m[5]*m[10] + m[12]*m[6]*m[9];
    inv[1]  = -m[1]*m[10]*m[15] + m[1]*m[11]*m[14] + m[9]*m[2]*m[15] - m[9]*m[3]*m[14] - m[13]*m[2]*m[11] + m[13]*m[3]*m[10];
    inv[5]  =  m[0]*m[10]*m[15] - m[0]*m[11]*m[14] - m[8]*m[2]*m[15] + m[8]*m[3]*m[14] + m[12]*m[2]*m[11] - m[12]*m[3]*m[10];
    inv[9]  = -m[0]*m[9]*m[15]  + m[0]*m[11]*m[13] + m[8]*m[1]*m[15] - m[8]*m[3]*m[13] - m[12]*m[1]*m[11] + m[12]*m[3]*m[9];
    inv[13] =  m[0]*m[9]*m[14]  - m[0]*m[10]*m[13] - m[8]*m[1]*m[14] + m[8]*m[2]*m[13] + m[12]*m[1]*m[10] - m[12]*m[2]*m[9];
    inv[2]  =  m[1]*m[6]*m[15]  - m[1]*m[7]*m[14]  - m[5]*m[2]*m[15] + m[5]*m[3]*m[14] + m[13]*m[2]*m[7]  - m[13]*m[3]*m[6];
    inv[6]  = -m[0]*m[6]*m[15]  + m[0]*m[7]*m[14]  + m[4]*m[2]*m[15] - m[4]*m[3]*m[14] - m[12]*m[2]*m[7]  + m[12]*m[3]*m[6];
    inv[10] =  m[0]*m[5]*m[15]  - m[0]*m[7]*m[13]  - m[4]*m[1]*m[15] + m[4]*m[3]*m[13] + m[12]*m[1]*m[7]  - m[12]*m[3]*m[5];
    inv[14] = -m[0]*m[5]*m[14]  + m[0]*m[6]*m[13]  + m[4]*m[1]*m[14] - m[4]*m[2]*m[13] - m[12]*m[1]*m[6]  + m[12]*m[2]*m[5];
    inv[3]  = -m[1]*m[6]*m[11]  + m[1]*m[7]*m[10]  + m[5]*m[2]*m[11] - m[5]*m[3]*m[10] - m[9]*m[2]*m[7]   + m[9]*m[3]*m[6];
    inv[7]  =  m[0]*m[6]*m[11]  - m[0]*m[7]*m[10]  - m[4]*m[2]*m[11] + m[4]*m[3]*m[10] + m[8]*m[2]*m[7]   - m[8]*m[3]*m[6];
    inv[11] = -m[0]*m[5]*m[11]  + m[0]*m[7]*m[9]   + m[4]*m[1]*m[11] - m[4]*m[3]*m[9]  - m[8]*m[1]*m[7]   + m[8]*m[3]*m[5];
    inv[15] =  m[0]*m[5]*m[10]  - m[0]*m[6]*m[9]   - m[4]*m[1]*m[10] + m[4]*m[2]*m[9]  + m[8]*m[1]*m[6]   - m[8]*m[2]*m[5];
    float det = m[0]*inv[0] + m[1]*inv[4] + m[2]*inv[8] + m[3]*inv[12];
    det = 1.0f / det;
    #pragma unroll
    for (int i = 0; i < 16; ++i) inv[i] *= det;
}

// ===========================================================================
// LEGACY single-kernel path (fallback when workspace is too small)
// ===========================================================================
constexpr int NZ  = 8;
constexpr int RB  = 1024;
constexpr int CAP = 1024;

constexpr int L_T    = 0;
constexpr int L_CNT  = 512;
constexpr int L_SIDX = 528;
constexpr int L_OVL  = L_SIDX + CAP;
constexpr int L_PRM  = L_OVL;
constexpr int L_KEYS = L_PRM + CAP * 8;
constexpr int L_ACC  = L_OVL;
constexpr int ACC_ST = 66;
constexpr int L_TOTAL = L_OVL + NZ * 64 * ACC_ST;

__global__ __launch_bounds__(RB, 4) void fused_render_kernel(
    const float* __restrict__ means,  const float* __restrict__ quats,
    const float* __restrict__ scales, const float* __restrict__ opac_logits,
    const float* __restrict__ colors, const float* __restrict__ c2o,
    const float* __restrict__ Kmat,   float* __restrict__ out)
{
    extern __shared__ float lds[];
    int*                cnt  = (int*)(lds + L_CNT);
    int*                sidx = (int*)(lds + L_SIDX);
    unsigned long long* keys = (unsigned long long*)(lds + L_KEYS);
    float4*             prm4 = (float4*)(lds + L_PRM);

    const int tid  = threadIdx.x;
    const int lane = tid & 63;
    const int wv16 = tid >> 6;
    const int sz   = wv16 >> 1;
    const int hh   = wv16 & 1;
    const int tile = blockIdx.x;
    const int tx = (tile & 15) * 8;
    const int ty = (tile >> 4) * 8;
    const float px = tx + (lane & 7) + 0.5f;
    const float py = ty + (lane >> 3) + 0.5f;
    const float cxt = tx + 4.0f, cyt = ty + 4.0f;

    if (tid == 0) *cnt = 0;
    __syncthreads();

    {
        float inv[16];
        {
            float m[16];
            #pragma unroll
            for (int t = 0; t < 16; ++t) m[t] = c2o[t];
            invert4x4(m, inv);
        }
        const float fx = Kmat[0], fy = Kmat[4], cx = Kmat[2], cy = Kmat[5];

        #pragma unroll
        for (int c = 0; c < NG / RB; ++c) {
            const int g = c * RB + tid;
            float mx = means[g*3+0], my = means[g*3+1], mz = means[g*3+2];
            float X = inv[0]*mx + inv[1]*my + inv[2]*mz  + inv[3];
            float Y = inv[4]*mx + inv[5]*my + inv[6]*mz  + inv[7];
            float Z = inv[8]*mx + inv[9]*my + inv[10]*mz + inv[11];

            float qw = quats[g*4+0], qx = quats[g*4+1], qy = quats[g*4+2], qz = quats[g*4+3];
            float qn = rsqrtf(qw*qw + qx*qx + qy*qy + qz*qz);
            qw *= qn; qx *= qn; qy *= qn; qz *= qn;
            float R00 = 1.f - 2.f*(qy*qy + qz*qz), R01 = 2.f*(qx*qy - qw*qz), R02 = 2.f*(qx*qz + qw*qy);
            float R10 = 2.f*(qx*qy + qw*qz), R11 = 1.f - 2.f*(qx*qx + qz*qz), R12 = 2.f*(qy*qz - qw*qx);
            float R20 = 2.f*(qx*qz - qw*qy), R21 = 2.f*(qy*qz + qw*qx), R22 = 1.f - 2.f*(qx*qx + qy*qy);

            float s0 = expf(scales[g*3+0]), s1 = expf(scales[g*3+1]), s2 = expf(scales[g*3+2]);
            float M00 = R00*s0, M01 = R01*s1, M02 = R02*s2;
            float M10 = R10*s0, M11 = R11*s1, M12 = R12*s2;
            float M20 = R20*s0, M21 = R21*s1, M22 = R22*s2;

            float V00 = M00*M00 + M01*M01 + M02*M02;
            float V01 = M00*M10 + M01*M11 + M02*M12;
            float V02 = M00*M20 + M01*M21 + M02*M22;
            float V11 = M10*M10 + M11*M11 + M12*M12;
            float V12 = M10*M20 + M11*M21 + M12*M22;
            float V22 = M20*M20 + M21*M21 + M22*M22;

            float Rv[3][3] = {{inv[0],inv[1],inv[2]},{inv[4],inv[5],inv[6]},{inv[8],inv[9],inv[10]}};
            float Vm[3][3] = {{V00,V01,V02},{V01,V11,V12},{V02,V12,V22}};
            float Tm[3][3], C[3][3];
            #pragma unroll
            for (int r = 0; r < 3; ++r)
                #pragma unroll
                for (int cc = 0; cc < 3; ++cc)
                    Tm[r][cc] = Rv[r][0]*Vm[0][cc] + Rv[r][1]*Vm[1][cc] + Rv[r][2]*Vm[2][cc];
            #pragma unroll
            for (int r = 0; r < 3; ++r)
                #pragma unroll
                for (int cc = 0; cc < 3; ++cc)
                    C[r][cc] = Tm[r][0]*Rv[cc][0] + Tm[r][1]*Rv[cc][1] + Tm[r][2]*Rv[cc][2];

            float rz = 1.0f / Z;
            float j00 = fx*rz, j02 = -fx*X*rz*rz;
            float j11 = fy*rz, j12 = -fy*Y*rz*rz;

            float c00 = j00*j00*C[0][0] + 2.f*j00*j02*C[0][2] + j02*j02*C[2][2];
            float c01 = j00*j11*C[0][1] + j00*j12*C[0][2] + j02*j11*C[1][2] + j02*j12*C[2][2];
            float c11 = j11*j11*C[1][1] + 2.f*j11*j12*C[1][2] + j12*j12*C[2][2];

            float a = c00 + P_BLUR;
            float b = c01;
            float cc_ = c11 + P_BLUR;
            float det = a*cc_ - b*b;

            float pmx = fx*X*rz + cx;
            float pmy = fy*Y*rz + cy;

            float lam = 0.5f*(a + cc_) + sqrtf(fmaxf(0.25f*(a - cc_)*(a - cc_) + b*b, 1e-12f));
            float radius = 3.0f * sqrtf(lam);
            bool valid = (Z > P_NEAR) && (det > 0.0f) && (radius > 3.0f);

            float op = 1.0f / (1.0f + expf(-opac_logits[g]));

            bool sel = false;
            float cA = 0.f, cB = 0.f, cC2 = 0.f;
            if (valid) {
                float rdet = 1.0f / det;
                cA = cc_ * rdet; cB = -b * rdet; cC2 = a * rdet;
                float smax = logf(255.0f * op);
                if (smax > 0.f) {
                    float rx = sqrtf(2.f * a   * smax) * 1.0001f + 1e-3f;
                    float ry = sqrtf(2.f * cc_ * smax) * 1.0001f + 1e-3f;
                    sel = (fabsf(pmx - cxt) <= rx + 3.5f) && (fabsf(pmy - cyt) <= ry + 3.5f);
                }
            }

            unsigned long long m = __ballot(sel);
            int wbase = 0;
            if (lane == 0 && m) wbase = atomicAdd(cnt, (int)__popcll(m));
            wbase = __shfl(wbase, 0);
            if (sel) {
                int pos = wbase + (int)__popcll(m & ((1ull << lane) - 1ull));
                if (pos < CAP) {
                    prm4[pos*2]   = make_float4(pmx, pmy, cA, cB);
                    prm4[pos*2+1] = make_float4(cC2, op, __int_as_float(g), 0.f);
                    keys[pos] = ((unsigned long long)__float_as_uint(Z) << 32) | (unsigned)g;
                }
            }
        }
    }
    __syncthreads();
    int L = *cnt;
    if (L > CAP) L = CAP;

    {
        int padL = (L + 1) & ~1;
        if (tid < padL - L) keys[L + tid] = ~0ull;
        __syncthreads();
        const ulonglong2* k2 = (const ulonglong2*)keys;
        if (tid < L) {
            unsigned long long kk = keys[tid];
            int rank = 0;
            #pragma unroll 2
            for (int c = 0; c < padL / 2; ++c) {
                ulonglong2 q = k2[c];
                rank += (q.x < kk) + (q.y < kk);
            }
            sidx[rank] = tid;
        }
    }
    __syncthreads();

    float acc[32];
    #pragma unroll
    for (int f = 0; f < 32; ++f) acc[f] = 0.f;
    float T = 1.0f;

    {
        const int r0 = (sz * L) >> 3;
        const int r1 = ((sz + 1) * L) >> 3;
        const float4* cph = (const float4*)colors + hh * 8;
        if (r1 > r0) {
            int k = sidx[r0];
            float4 e0 = prm4[k*2], e1 = prm4[k*2+1];
            for (int r = r0; r < r1; ++r) {
                int kn = (r + 1 < r1) ? sidx[r + 1] : k;
                float4 n0 = prm4[kn*2], n1 = prm4[kn*2+1];

                float dx = px - e0.x, dy = py - e0.y;
                float sig = 0.5f*(e0.z*dx*dx + e1.x*dy*dy) + e0.w*dx*dy;
                float al = fminf(e1.y * __expf(-sig), P_AMAX);
                al = (sig >= 0.f && al >= P_AMIN) ? al : 0.f;

                if (__ballot(al > 0.f)) {
                    float wv = T * al;
                    const float4* crow = cph + (size_t)(unsigned)__float_as_int(e1.z) * 16;
                    #pragma unroll
                    for (int q = 0; q < 8; ++q) {
                        float4 cv = crow[q];
                        acc[4*q+0] = fmaf(wv, cv.x, acc[4*q+0]);
                        acc[4*q+1] = fmaf(wv, cv.y, acc[4*q+1]);
                        acc[4*q+2] = fmaf(wv, cv.z, acc[4*q+2]);
                        acc[4*q+3] = fmaf(wv, cv.w, acc[4*q+3]);
                    }
                    T *= (1.f - al);
                    if (!__ballot(T >= 1e-6f)) break;
                }
                e0 = n0; e1 = n1; k = kn;
            }
        }
    }

    if (hh == 0) lds[L_T + sz*64 + lane] = T;
    __syncthreads();
    {
        float* ab = lds + L_ACC + (size_t)(sz * 64 + lane) * ACC_ST + hh * 32;
        #pragma unroll
        for (int q = 0; q < 16; ++q)
            *(float2*)(ab + 2*q) = make_float2(acc[2*q], acc[2*q+1]);
    }
    __syncthreads();

    {
        int p  = tid >> 4;
        int f0 = (tid & 15) * 4;
        float r0, r1, r2, r3;
        const float* ab = lds + L_ACC + (size_t)((NZ-1)*64 + p) * ACC_ST + f0;
        { float2 u = *(const float2*)ab, v = *(const float2*)(ab + 2);
          r0 = u.x; r1 = u.y; r2 = v.x; r3 = v.y; }
        #pragma unroll
        for (int s = NZ - 2; s >= 0; --s) {
            float Ts = lds[L_T + s*64 + p];
            const float* as_ = lds + L_ACC + (size_t)(s*64 + p) * ACC_ST + f0;
            float2 u = *(const float2*)as_, v = *(const float2*)(as_ + 2);
            r0 = fmaf(Ts, r0, u.x); r1 = fmaf(Ts, r1, u.y);
            r2 = fmaf(Ts, r2, v.x); r3 = fmaf(Ts, r3, v.y);
        }
        int pyg = ty + (p >> 3), pxg = tx + (p & 7);
        float* op_ = out + (size_t)(pyg * IW + pxg) * DF + f0;
        *(float4*)op_ = make_float4(r0, r1, r2, r3);
    }
}

// ===========================================================================
// 2-kernel pipeline (R8).
// R7 post-mortem: 104.2us; both kernels < 40us fills.  Raster is VALU-issue
// bound where resident (colors on scalar pipe; LDS/SMEM latency TLP-hidden
// at 16 waves/CU).  R8 = pure instruction-count trims:
//  (1) drop prm prefetch rotation (direct ds_read per row, no e0=n0 movs)
//  (2) pre-halve cA/cC2 in prep -> sig has one fewer mul
//  (3) cull 8 barriers -> 2 (batch 4 chunk ballots, one prefix)
//  (4) epilogue 8 passes -> 4 (8 floats/row staged, all 512 thr combine)
// ===========================================================================
constexpr int ZSL    = 8;     // z-slices per raster block (= waves per block)
constexpr int NFB    = 2;     // feature-blocks per tile (32 feats each)
constexpr int RTH    = 512;   // raster block threads
constexpr int NTILES = 256;
constexpr int EST    = 12;    // epilogue stage stride (floats), 16B-aligned

// workspace layout (float offsets) — ~106 KB total
constexpr size_t WS_SA   = 0;                       // sorted A {pmx,pmy,cA/2,cB}
constexpr size_t WS_SB   = WS_SA   + NG*4;          // sorted B {cC2/2,op,rx,ry}
constexpr size_t WS_SC   = WS_SB   + NG*4;          // sorted cull {pmx,pmy,rx,ry}
constexpr size_t WS_SG   = WS_SC   + NG*4;          // sorted gaussian idx
constexpr size_t WS_TOTAL= WS_SG   + NG;

// ---- K1: fused preprocess + global stable z-sort + scatter ----------------
__global__ __launch_bounds__(512) void prep_sort_kernel(
    const float* __restrict__ means,  const float* __restrict__ quats,
    const float* __restrict__ scales, const float* __restrict__ opac_logits,
    const float* __restrict__ c2o,    const float* __restrict__ Kmat,
    float* __restrict__ ws)
{
    __shared__ __align__(16) unsigned zlds[NG];
    __shared__ int cnt[8][64];
    const int tid  = threadIdx.x;
    const int lane = tid & 63;
    const int part = tid >> 6;
    const int b    = blockIdx.x;
    const int gown = b * 64 + lane;

    float inv[16];
    {
        float m[16];
        #pragma unroll
        for (int t = 0; t < 16; ++t) m[t] = c2o[t];
        invert4x4(m, inv);
    }
    const float fx = Kmat[0], fy = Kmat[4], cx = Kmat[2], cy = Kmat[5];

    // ---- all 2048 z-keys (4 per thread), deterministic across blocks
    #pragma unroll
    for (int u = 0; u < NG/512; ++u) {
        const int g = u*512 + tid;
        float mx = means[g*3+0], my = means[g*3+1], mz = means[g*3+2];
        float Z = inv[8]*mx + inv[9]*my + inv[10]*mz + inv[11];
        zlds[g] = __float_as_uint(Z);   // Z>0 for contributors: uint order == float order
    }

    // ---- wave 0: full preprocess of own gaussian (registers)
    float4 A = make_float4(0.f,0.f,0.f,0.f);
    float4 B = make_float4(0.f,0.f,-1e9f,-1e9f);
    if (part == 0) {
        const int g = gown;
        float mx = means[g*3+0], my = means[g*3+1], mz = means[g*3+2];
        float X = inv[0]*mx + inv[1]*my + inv[2]*mz  + inv[3];
        float Y = inv[4]*mx + inv[5]*my + inv[6]*mz  + inv[7];
        float Z = inv[8]*mx + inv[9]*my + inv[10]*mz + inv[11];

        float qw = quats[g*4+0], qx = quats[g*4+1], qy = quats[g*4+2], qz = quats[g*4+3];
        float qn = rsqrtf(qw*qw + qx*qx + qy*qy + qz*qz);
        qw *= qn; qx *= qn; qy *= qn; qz *= qn;
        float R00 = 1.f - 2.f*(qy*qy + qz*qz), R01 = 2.f*(qx*qy - qw*qz), R02 = 2.f*(qx*qz + qw*qy);
        float R10 = 2.f*(qx*qy + qw*qz), R11 = 1.f - 2.f*(qx*qx + qz*qz), R12 = 2.f*(qy*qz - qw*qx);
        float R20 = 2.f*(qx*qz - qw*qy), R21 = 2.f*(qy*qz + qw*qx), R22 = 1.f - 2.f*(qx*qx + qy*qy);

        float s0 = expf(scales[g*3+0]), s1 = expf(scales[g*3+1]), s2 = expf(scales[g*3+2]);
        float M00 = R00*s0, M01 = R01*s1, M02 = R02*s2;
        float M10 = R10*s0, M11 = R11*s1, M12 = R12*s2;
        float M20 = R20*s0, M21 = R21*s1, M22 = R22*s2;

        float V00 = M00*M00 + M01*M01 + M02*M02;
        float V01 = M00*M10 + M01*M11 + M02*M12;
        float V02 = M00*M20 + M01*M21 + M02*M22;
        float V11 = M10*M10 + M11*M11 + M12*M12;
        float V12 = M10*M20 + M11*M21 + M12*M22;
        float V22 = M20*M20 + M21*M21 + M22*M22;

        float Rv[3][3] = {{inv[0],inv[1],inv[2]},{inv[4],inv[5],inv[6]},{inv[8],inv[9],inv[10]}};
        float Vm[3][3] = {{V00,V01,V02},{V01,V11,V12},{V02,V12,V22}};
        float Tm[3][3], C[3][3];
        #pragma unroll
        for (int r = 0; r < 3; ++r)
            #pragma unroll
            for (int cc = 0; cc < 3; ++cc)
                Tm[r][cc] = Rv[r][0]*Vm[0][cc] + Rv[r][1]*Vm[1][cc] + Rv[r][2]*Vm[2][cc];
        #pragma unroll
        for (int r = 0; r < 3; ++r)
            #pragma unroll
            for (int cc = 0; cc < 3; ++cc)
                C[r][cc] = Tm[r][0]*Rv[cc][0] + Tm[r][1]*Rv[cc][1] + Tm[r][2]*Rv[cc][2];

        float rz = 1.0f / Z;
        float j00 = fx*rz, j02 = -fx*X*rz*rz;
        float j11 = fy*rz, j12 = -fy*Y*rz*rz;

        float c00 = j00*j00*C[0][0] + 2.f*j00*j02*C[0][2] + j02*j02*C[2][2];
        float c01 = j00*j11*C[0][1] + j00*j12*C[0][2] + j02*j11*C[1][2] + j02*j12*C[2][2];
        float c11 = j11*j11*C[1][1] + 2.f*j11*j12*C[1][2] + j12*j12*C[2][2];

        float a = c00 + P_BLUR;
        float bb = c01;
        float cc_ = c11 + P_BLUR;
        float det = a*cc_ - bb*bb;

        float pmx = fx*X*rz + cx;
        float pmy = fy*Y*rz + cy;

        float lam = 0.5f*(a + cc_) + sqrtf(fmaxf(0.25f*(a - cc_)*(a - cc_) + bb*bb, 1e-12f));
        float radius = 3.0f * sqrtf(lam);
        bool valid = (Z > P_NEAR) && (det > 0.0f) && (radius > 3.0f);

        float op = 1.0f / (1.0f + expf(-opac_logits[g]));

        float cA = 0.f, cB = 0.f, cC2 = 0.f, rx = -1e9f, ry = -1e9f;
        if (valid) {
            float rdet = 1.0f / det;
            cA = cc_ * rdet; cB = -bb * rdet; cC2 = a * rdet;
            float smax = logf(255.0f * op);
            if (smax > 0.f) {
                rx = sqrtf(2.f * a   * smax) * 1.0001f + 1e-3f;
                ry = sqrtf(2.f * cc_ * smax) * 1.0001f + 1e-3f;
            }
        }
        // pre-halved quadratic coefficients: sig = A.z*dx^2 + B.x*dy^2 + A.w*dx*dy
        A = make_float4(pmx, pmy, 0.5f*cA, cB);
        B = make_float4(0.5f*cC2, op, rx, ry);
    }
    __syncthreads();

    // ---- rank own 64 gaussians against all 2048 (z,idx) keys
    const unsigned kk = zlds[b*64 + lane];
    const uint4* zl4 = (const uint4*)zlds;
    int c = 0;
    #pragma unroll 4
    for (int i = part*64; i < part*64 + 64; ++i) {
        uint4 q = zl4[i];
        const int j = i * 4;
        c += (q.x < kk || (q.x == kk && j+0 < gown)) ? 1 : 0;
        c += (q.y < kk || (q.y == kk && j+1 < gown)) ? 1 : 0;
        c += (q.z < kk || (q.z == kk && j+2 < gown)) ? 1 : 0;
        c += (q.w < kk || (q.w == kk && j+3 < gown)) ? 1 : 0;
    }
    cnt[part][lane] = c;
    __syncthreads();
    if (part == 0) {
        int rank = 0;
        #pragma unroll
        for (int e = 0; e < 8; ++e) rank += cnt[e][lane];
        ((float4*)(ws + WS_SA))[rank] = A;
        ((float4*)(ws + WS_SB))[rank] = B;
        ((float4*)(ws + WS_SC))[rank] = make_float4(A.x, A.y, B.z, B.w);
        ((int*)  (ws + WS_SG))[rank] = gown;
    }
}

// ---- K2: raster. grid = NTILES*NFB = 512; block = 512 thr = 8 waves ------
// bid -> tile = bid>>1, fb = bid&1 (32-feature block).  Inline 2-barrier
// cull, direct-row composite (slice w, rows [w*L/8,(w+1)*L/8), acc[32]),
// 4-pass epilogue affine over all 8 slices -> out.  No combine kernel.
__global__ __launch_bounds__(RTH) void raster_kernel(
    const float* __restrict__ colors, float* __restrict__ ws,
    float* __restrict__ out)
{
    __shared__ float ureg[CAP*8];        // culled prm list; epilogue overlays
    __shared__ float Tlds[ZSL*64];
    __shared__ int   s_cnt[4][8];        // [chunk][wave]

    const int tid  = threadIdx.x;
    const int lane = tid & 63;
    const int w    = tid >> 6;           // wave 0..7 = z-slice
    const int b    = blockIdx.x;
    const int tile = b >> 1;
    const int fb   = b & 1;
    const int tx = (tile & 15) * 8, ty = (tile >> 4) * 8;
    const float px = tx + (lane & 7) + 0.5f;
    const float py = ty + (lane >> 3) + 0.5f;
    const float cxt = tx + 4.0f, cyt = ty + 4.0f;

    float4* prm4 = (float4*)ureg;
    const float4* sA = (const float4*)(ws + WS_SA);
    const float4* sB = (const float4*)(ws + WS_SB);
    const float4* sC = (const float4*)(ws + WS_SC);
    const int*    sG = (const int*)  (ws + WS_SG);

    // ---- inline cull, 2 barriers: batch all 4 chunk ballots, one prefix
    unsigned long long msk[4];
    bool selv[4];
    {
        float4 Cv[4];
        #pragma unroll
        for (int ch = 0; ch < 4; ++ch) Cv[ch] = sC[ch*RTH + tid];
        #pragma unroll
        for (int ch = 0; ch < 4; ++ch) {
            bool sel = (fabsf(Cv[ch].x - cxt) <= Cv[ch].z + 3.5f) &&
                       (fabsf(Cv[ch].y - cyt) <= Cv[ch].w + 3.5f);
            selv[ch] = sel;
            msk[ch]  = __ballot(sel);
            if (lane == 0) s_cnt[ch][w] = (int)__popcll(msk[ch]);
        }
    }
    __syncthreads();
    int Ltot, mypos[4];
    {
        int run = 0;
        const uint4* cc4 = (const uint4*)s_cnt;   // 32 ints = 8 uint4
        #pragma unroll
        for (int q = 0; q < 8; ++q) {
            uint4 v = cc4[q];
            int vals[4] = {(int)v.x, (int)v.y, (int)v.z, (int)v.w};
            #pragma unroll
            for (int t = 0; t < 4; ++t) {
                int lin = q*4 + t, ch = lin >> 3, e = lin & 7;
                if (e == w) mypos[ch] = run;
                run += vals[t];
            }
        }
        Ltot = run;
    }
    #pragma unroll
    for (int ch = 0; ch < 4; ++ch) {
        if (selv[ch]) {
            int pos = mypos[ch] + (int)__popcll(msk[ch] & ((1ull << lane) - 1ull));
            if (pos < CAP) {
                const int j = ch*RTH + tid;
                float4 Aa = sA[j], Bb = sB[j];
                prm4[pos*2]   = Aa;
                prm4[pos*2+1] = make_float4(Bb.x, Bb.y, __int_as_float(sG[j]), 0.f);
            }
        }
    }
    __syncthreads();
    const int L = (Ltot < CAP) ? Ltot : CAP;

    // ---- composite: slice w, rows [w*L/8, (w+1)*L/8), direct row loads
    float acc[32];
    #pragma unroll
    for (int i = 0; i < 32; ++i) acc[i] = 0.f;
    float T = 1.0f;
    {
        const int r0 = (w * L) >> 3;
        const int r1 = ((w + 1) * L) >> 3;
        const float4* cph = (const float4*)colors + fb * 8;
        for (int r = r0; r < r1; ++r) {
            float4 e0 = prm4[2*r], e1 = prm4[2*r+1];
            // colors: wave-uniform index -> readfirstlane -> scalar loads
            const int gi = __builtin_amdgcn_readfirstlane(__float_as_int(e1.z));
            const float4* crow = cph + (size_t)(unsigned)gi * (DF/4);
            float4 c0 = crow[0], c1 = crow[1], c2 = crow[2], c3 = crow[3];
            float4 c4 = crow[4], c5 = crow[5], c6 = crow[6], c7 = crow[7];

            float dx = px - e0.x, dy = py - e0.y;
            float sig = e0.z*dx*dx + e1.x*dy*dy + e0.w*dx*dy;   // pre-halved coeffs
            float al = fminf(e1.y * __expf(-sig), P_AMAX);
            al = (sig >= 0.f && al >= P_AMIN) ? al : 0.f;

            if (__ballot(al > 0.f)) {
                float wv = T * al;
                acc[0]  = fmaf(wv, c0.x, acc[0]);  acc[1]  = fmaf(wv, c0.y, acc[1]);
                acc[2]  = fmaf(wv, c0.z, acc[2]);  acc[3]  = fmaf(wv, c0.w, acc[3]);
                acc[4]  = fmaf(wv, c1.x, acc[4]);  acc[5]  = fmaf(wv, c1.y, acc[5]);
                acc[6]  = fmaf(wv, c1.z, acc[6]);  acc[7]  = fmaf(wv, c1.w, acc[7]);
                acc[8]  = fmaf(wv, c2.x, acc[8]);  acc[9]  = fmaf(wv, c2.y, acc[9]);
                acc[10] = fmaf(wv, c2.z, acc[10]); acc[11] = fmaf(wv, c2.w, acc[11]);
                acc[12] = fmaf(wv, c3.x, acc[12]); acc[13] = fmaf(wv, c3.y, acc[13]);
                acc[14] = fmaf(wv, c3.z, acc[14]); acc[15] = fmaf(wv, c3.w, acc[15]);
                acc[16] = fmaf(wv, c4.x, acc[16]); acc[17] = fmaf(wv, c4.y, acc[17]);
                acc[18] = fmaf(wv, c4.z, acc[18]); acc[19] = fmaf(wv, c4.w, acc[19]);
                acc[20] = fmaf(wv, c5.x, acc[20]); acc[21] = fmaf(wv, c5.y, acc[21]);
                acc[22] = fmaf(wv, c5.z, acc[22]); acc[23] = fmaf(wv, c5.w, acc[23]);
                acc[24] = fmaf(wv, c6.x, acc[24]); acc[25] = fmaf(wv, c6.y, acc[25]);
                acc[26] = fmaf(wv, c6.z, acc[26]); acc[27] = fmaf(wv, c6.w, acc[27]);
                acc[28] = fmaf(wv, c7.x, acc[28]); acc[29] = fmaf(wv, c7.y, acc[29]);
                acc[30] = fmaf(wv, c7.z, acc[30]); acc[31] = fmaf(wv, c7.w, acc[31]);
                T *= (1.f - al);
                if (!__ballot(T >= 1e-6f)) break;   // whole wave saturated
            }
        }
    }

    // ---- stage T; barrier also ends prm reads before the staging overlay
    Tlds[w*64 + lane] = T;
    __syncthreads();

    // ---- 4 passes x 8 features: stage slice accs + affine combine + store.
    // Stage row = w*64+lane (512 rows, stride EST=12, 8 floats/row;
    // max idx 511*12+8 = 6140 < 8192).  out = a0 + T0*(a1 + T1*(...)).
    #pragma unroll
    for (int pass = 0; pass < 4; ++pass) {
        float* ab = ureg + (w*64 + lane) * EST;
        *(float4*)(ab)     = make_float4(acc[pass*8+0], acc[pass*8+1], acc[pass*8+2], acc[pass*8+3]);
        *(float4*)(ab + 4) = make_float4(acc[pass*8+4], acc[pass*8+5], acc[pass*8+6], acc[pass*8+7]);
        __syncthreads();
        {
            const int p = tid >> 3, c = tid & 7;     // pixel 0..63, feat-in-pass
            float r = ureg[((ZSL-1)*64 + p)*EST + c];
            #pragma unroll
            for (int s = ZSL-2; s >= 0; --s)
                r = fmaf(Tlds[s*64 + p], r, ureg[(s*64 + p)*EST + c]);
            const int pxg = tx + (p & 7), pyg = ty + (p >> 3);
            const int fi = fb*32 + pass*8 + c;
            out[(size_t)(pyg*IW + pxg)*DF + fi] = r;
        }
        __syncthreads();
    }
}

// ---------------------------------------------------------------------------
extern "C" void kernel_launch(void* const* d_in, const int* in_sizes, int n_in,
                              void* d_out, int out_size, void* d_ws, size_t ws_size,
                              hipStream_t stream) {
    const float* means  = (const float*)d_in[0];
    const float* quats  = (const float*)d_in[1];
    const float* scales = (const float*)d_in[2];
    const float* opac   = (const float*)d_in[3];
    const float* colors = (const float*)d_in[4];
    const float* c2o    = (const float*)d_in[5];
    const float* Kmat   = (const float*)d_in[6];
    float* out = (float*)d_out;

    if (ws_size >= WS_TOTAL * sizeof(float)) {
        float* ws = (float*)d_ws;
        prep_sort_kernel<<<NG/64,        512, 0, stream>>>(means, quats, scales, opac, c2o, Kmat, ws);
        raster_kernel   <<<NTILES*NFB,   RTH, 0, stream>>>(colors, ws, out);
    } else {
        // fallback: legacy fused single-kernel path
        (void)hipFuncSetAttribute((const void*)fused_render_kernel,
                                  hipFuncAttributeMaxDynamicSharedMemorySize,
                                  L_TOTAL * 4);
        fused_render_kernel<<<IH*IW/64, RB, L_TOTAL*4, stream>>>(
            means, quats, scales, opac, colors, c2o, Kmat, out);
    }
}